// Round 12
// baseline (365.391 us; speedup 1.0000x reference)
//
#include <hip/hip_runtime.h>
#include <stdint.h>

#define B_SZ 2
#define S_LEN 2048
#define D_DIM 2048
#define NHEAD 16
#define HD 128
#define HALF 64
#define MROWS (B_SZ * S_LEN)   // 4096

typedef __attribute__((ext_vector_type(8))) __bf16 bf16x8;
typedef __attribute__((ext_vector_type(8))) unsigned short u16x8;
typedef __attribute__((ext_vector_type(4))) float f32x4;
typedef __attribute__((ext_vector_type(16))) float f32x16;
typedef __attribute__((ext_vector_type(4))) unsigned int u32x4;

__device__ inline unsigned short f2bf(float x) {
  union { float f; uint32_t u; } c; c.f = x;
  uint32_t r = (c.u + 0x7fffu + ((c.u >> 16) & 1u)) >> 16;
  return (unsigned short)r;
}

__device__ inline float bf2f(unsigned short b) {
  union { uint32_t u; float f; } c; c.u = (uint32_t)b << 16;
  return c.f;
}

__device__ inline void gll16(const void* g, void* l) {
  __builtin_amdgcn_global_load_lds(
      (const __attribute__((address_space(1))) void*)g,
      (__attribute__((address_space(3))) void*)l,
      16, 0, 0);
}

// ---------------- fused cast f32 -> bf16 for x + 4 weight matrices ----------------
__global__ void cast_all(const float* __restrict__ x,
                         const float* __restrict__ qw, const float* __restrict__ kw,
                         const float* __restrict__ vw, const float* __restrict__ ow,
                         unsigned short* __restrict__ xb,
                         unsigned short* __restrict__ qwb, unsigned short* __restrict__ kwb,
                         unsigned short* __restrict__ vwb, unsigned short* __restrict__ owb) {
  const int n_x = (MROWS * D_DIM) / 4;
  const int n_w = (D_DIM * D_DIM) / 4;      // == 1<<20
  const int total = n_x + 4 * n_w;
  int i = blockIdx.x * blockDim.x + threadIdx.x;
  int stride = gridDim.x * blockDim.x;
  for (; i < total; i += stride) {
    const float* src; unsigned short* dst; int off;
    if (i < n_x) { src = x; dst = xb; off = i; }
    else {
      int j = i - n_x;
      int seg = j >> 20;
      off = j & (n_w - 1);
      src = seg == 0 ? qw : seg == 1 ? kw : seg == 2 ? vw : ow;
      dst = seg == 0 ? qwb : seg == 1 ? kwb : seg == 2 ? vwb : owb;
    }
    float4 v = reinterpret_cast<const float4*>(src)[off];
    ushort4 o;
    o.x = f2bf(v.x); o.y = f2bf(v.y); o.z = f2bf(v.z); o.w = f2bf(v.w);
    reinterpret_cast<ushort4*>(dst)[off] = o;
  }
}

// ---------------- GEMM 128x256 tile, BK=64, 8 waves, tri-buffered counted-vmcnt ----------------
// C[i,j] = sum_k A[i,k]*Bt[j,k] + bias[j].
// Block map is bn-MAJOR within each XCD chunk (bm = lin & 31, bn = lin >> 5):
// the ~32 co-resident blocks per XCD share ONE 1MB B-panel (L2-resident) and
// stream A panels (L3-shared across XCDs). Round-11 lesson: row-major mapping
// gave zero concurrent B reuse -> 307MB HBM fetch, 167us.
// MODE 0: fp32 linear out -> C0.
// MODE 3: QKV fused (N=6144): col seg 0 -> (ushort*)C0 bf16 linear [row][2048],
//         seg 1 -> C1 bf16 linear, seg 2 -> C2 = Vt2[b][h][s/64][d][s%64].
// LDS: A 3x16KB + B 3x32KB = 144KB. XOR swizzle chunk^=(row&7) (src-preswizzle + read).
// Per K-tile: stage(t+2) 6 loads; vmcnt(6) waits tile t only (t+1 stays in flight);
// 2 phases (kk halves) of {8 ds_read_b128; s_barrier; setprio+16 MFMA; s_barrier}.
template <int MODE>
__global__ __launch_bounds__(512) void gemm256(
    const unsigned short* __restrict__ A, const unsigned short* __restrict__ Bt,
    const float* __restrict__ bias, void* __restrict__ C0,
    unsigned short* __restrict__ C1, unsigned short* __restrict__ C2,
    int M, int N, int K) {
  __shared__ __align__(16) unsigned short As[3 * 128 * 64];   // 48KB
  __shared__ __align__(16) unsigned short Bs[3 * 256 * 64];   // 96KB
  const int tid = threadIdx.x;
  const int lane = tid & 63;
  const int wave = tid >> 6;            // 0..7
  const int lm = lane & 15, lg = lane >> 4;
  const int chunk = gridDim.x >> 3;     // grid % 8 == 0
  const int lin = (blockIdx.x & 7) * chunk + (blockIdx.x >> 3);
  const int bm = lin & 31;              // bn-major: M = 4096 fixed -> nbm = 32
  const int bn = lin >> 5;
  const int mwave = (wave >> 2) * 64;   // 0 / 64
  const int nwave = (wave & 3) * 64;    // 0..192

  f32x4 acc[4][4] = {};

  auto stage = [&](int slot, int kt) {  // 6 gll16 per thread
    const int k0 = kt * 64;
#pragma unroll
    for (int r = 0; r < 2; ++r) {
      int p = r * 8192 + tid * 16;
      int row = p >> 7, ch = (p >> 4) & 7;
      gll16(A + (size_t)(bm * 128 + row) * K + k0 + ((ch ^ (row & 7)) << 3),
            (char*)As + slot * 16384 + p);
    }
#pragma unroll
    for (int r = 0; r < 4; ++r) {
      int p = r * 8192 + tid * 16;
      int row = p >> 7, ch = (p >> 4) & 7;
      gll16(Bt + (size_t)(bn * 256 + row) * K + k0 + ((ch ^ (row & 7)) << 3),
            (char*)Bs + slot * 32768 + p);
    }
  };

  const int NT = K >> 6;                // 32
  stage(0, 0);
  stage(1, 1 < NT ? 1 : 0);

  int rd = 0, st = 2;
  for (int t = 0; t < NT; ++t) {
    stage(st, (t + 2 < NT) ? t + 2 : NT - 1);           // +6 (tile t+2, redundant at tail)
    asm volatile("s_waitcnt vmcnt(6)" ::: "memory");    // tile t's 6 done; t+1 in flight
    __builtin_amdgcn_sched_barrier(0);
    __builtin_amdgcn_s_barrier();                       // buf[rd] valid for all waves
    __builtin_amdgcn_sched_barrier(0);

    const char* abp = (const char*)As + rd * 16384;
    const char* bbp = (const char*)Bs + rd * 32768;
#pragma unroll
    for (int kk = 0; kk < 2; ++kk) {
      bf16x8 af[4], bf[4];
#pragma unroll
      for (int mi = 0; mi < 4; ++mi) {
        int row = mwave + mi * 16 + lm;
        af[mi] = *reinterpret_cast<const bf16x8*>(
            abp + row * 128 + ((((kk << 2) + lg) ^ (row & 7)) << 4));
      }
#pragma unroll
      for (int ni = 0; ni < 4; ++ni) {
        int row = nwave + ni * 16 + lm;
        bf[ni] = *reinterpret_cast<const bf16x8*>(
            bbp + row * 128 + ((((kk << 2) + lg) ^ (row & 7)) << 4));
      }
      __builtin_amdgcn_s_barrier();                     // phase align (role split)
      __builtin_amdgcn_sched_barrier(0);
      __builtin_amdgcn_s_setprio(1);
#pragma unroll
      for (int mi = 0; mi < 4; ++mi)
#pragma unroll
        for (int ni = 0; ni < 4; ++ni)
          acc[mi][ni] = __builtin_amdgcn_mfma_f32_16x16x32_bf16(
              af[mi], bf[ni], acc[mi][ni], 0, 0, 0);
      __builtin_amdgcn_s_setprio(0);
      __builtin_amdgcn_sched_barrier(0);
      __builtin_amdgcn_s_barrier();                     // phase end
      __builtin_amdgcn_sched_barrier(0);
    }
    // rotate slots: rd -> rd+1, st -> st+1 (mod 3)
    rd = (rd == 2) ? 0 : rd + 1;
    st = (st == 2) ? 0 : st + 1;
  }

  // ---------------- epilogue ----------------
#pragma unroll
  for (int ni = 0; ni < 4; ++ni) {
    int col = bn * 256 + nwave + ni * 16 + lm;
    float bv = bias[col];
    if constexpr (MODE == 3) {
      int seg = col >> 11;            // 0=Q, 1=K, 2=V
      int c2 = col & (D_DIM - 1);
#pragma unroll
      for (int mi = 0; mi < 4; ++mi) {
        int row0 = bm * 128 + mwave + mi * 16 + lg * 4;
        if (seg == 2) {
          int b = row0 >> 11, s0 = row0 & (S_LEN - 1);
          int h = c2 >> 7, d = c2 & (HD - 1);
          ushort4 o;
          o.x = f2bf(acc[mi][ni][0] + bv);
          o.y = f2bf(acc[mi][ni][1] + bv);
          o.z = f2bf(acc[mi][ni][2] + bv);
          o.w = f2bf(acc[mi][ni][3] + bv);
          size_t oi = ((((size_t)(b * NHEAD + h) * (S_LEN / 64) + (s0 >> 6)) * HD + d) << 6)
                      + (s0 & 63);
          *reinterpret_cast<ushort4*>(C2 + oi) = o;
        } else {
          unsigned short* dst = (seg == 0) ? (unsigned short*)C0 : C1;
#pragma unroll
          for (int r = 0; r < 4; ++r)
            dst[(size_t)(row0 + r) * D_DIM + c2] = f2bf(acc[mi][ni][r] + bv);
        }
      }
    } else {
      float* out = (float*)C0;
#pragma unroll
      for (int mi = 0; mi < 4; ++mi) {
        int row0 = bm * 128 + mwave + mi * 16 + lg * 4;
#pragma unroll
        for (int r = 0; r < 4; ++r)
          out[(size_t)(row0 + r) * N + col] = acc[mi][ni][r] + bv;
      }
    }
  }
}

// ---------------- RMSNorm (full D) + RoPE, bf16 in -> bf16 out, * outscale ----------------
// BLOCKED=0: linear [row][D]. BLOCKED=1: head-blocked Kh[b][h][s][d].
template <int BLOCKED>
__global__ __launch_bounds__(256) void norm_rope(
    const unsigned short* __restrict__ h, const float* __restrict__ w,
    const float* __restrict__ cosb, const float* __restrict__ sinb,
    unsigned short* __restrict__ out, float outscale) {
  const int row = blockIdx.x;
  const int pos = row & (S_LEN - 1);
  const unsigned short* hr = h + (size_t)row * D_DIM;
  const int t = threadIdx.x;
  const int d = t * 8;

  u16x8 hv = *reinterpret_cast<const u16x8*>(hr + d);
  float a[8];
#pragma unroll
  for (int i = 0; i < 8; ++i) a[i] = bf2f(hv[i]);
  float ss = 0.f;
#pragma unroll
  for (int i = 0; i < 8; ++i) ss += a[i] * a[i];
#pragma unroll
  for (int off = 32; off > 0; off >>= 1) ss += __shfl_down(ss, off);
  __shared__ float red[4];
  if ((t & 63) == 0) red[t >> 6] = ss;
  __syncthreads();
  float tot = red[0] + red[1] + red[2] + red[3];
  float inv = rsqrtf(tot * (1.0f / D_DIM) + 1e-6f) * outscale;

  const int p = (d & (HD - 1)) >> 1;
  const float* cp = cosb + pos * HALF + p;
  const float* sp = sinb + pos * HALF + p;
  const float* wp = w + d;

  float c0 = cp[0], c1 = cp[1], c2 = cp[2], c3 = cp[3];
  float s0 = sp[0], s1 = sp[1], s2 = sp[2], s3 = sp[3];
#pragma unroll
  for (int i = 0; i < 8; ++i) a[i] = a[i] * inv * wp[i];
  u16x8 o;
  o[0] = f2bf(a[0] * c0 - a[1] * s0);
  o[1] = f2bf(a[0] * s0 + a[1] * c0);
  o[2] = f2bf(a[2] * c1 - a[3] * s1);
  o[3] = f2bf(a[2] * s1 + a[3] * c1);
  o[4] = f2bf(a[4] * c2 - a[5] * s2);
  o[5] = f2bf(a[4] * s2 + a[5] * c2);
  o[6] = f2bf(a[6] * c3 - a[7] * s3);
  o[7] = f2bf(a[6] * s3 + a[7] * c3);
  if constexpr (BLOCKED) {
    int hh = t >> 4;            // head = d / HD
    int dd = d & (HD - 1);
    size_t oi = (((size_t)((row >> 11) * NHEAD + hh) * S_LEN) + pos) * HD + dd;
    *reinterpret_cast<u16x8*>(out + oi) = o;
  } else {
    *reinterpret_cast<u16x8*>(out + (size_t)row * D_DIM + d) = o;
  }
}

// ---------------- flash attention: 8 waves x 32q (QBLK=256), KVBLK=64 ----------------
// (unchanged from round 10: 105.6us, MfmaUtil 27%)
__global__ __launch_bounds__(512) void attn_kernel(
    const unsigned short* __restrict__ Q, const unsigned short* __restrict__ Kh,
    const unsigned short* __restrict__ Vt, unsigned short* __restrict__ O) {
  const int idx = blockIdx.x;
  const int swz = (idx & 7) * 32 + (idx >> 3);   // 256 blocks, 32/XCD (4 heads)
  const int qb = swz & 7;
  const int h = (swz >> 3) & 15;
  const int b = swz >> 7;

  const int tid = threadIdx.x;
  const int lane = tid & 63;
  const int wave = tid >> 6;          // 0..7
  const int l31 = lane & 31;
  const int hh = lane >> 5;

  const size_t qbase = (size_t)b * S_LEN * D_DIM + (size_t)h * HD;   // linear Q/O
  const size_t hbase = (size_t)(b * NHEAD + h) * S_LEN * HD;         // blocked K/V
  const int q0w = qb * 256 + wave * 32;

  __shared__ __align__(16) unsigned short Ks[2 * 64 * 128];  // 2 x 16KB (dbuf)
  __shared__ __align__(16) unsigned short Vs[128 * 64];      // 1 x 16KB

  bf16x8 qf[8];
#pragma unroll
  for (int ds_ = 0; ds_ < 8; ++ds_)
    qf[ds_] = *reinterpret_cast<const bf16x8*>(
        Q + qbase + (size_t)(q0w + l31) * D_DIM + ds_ * 16 + hh * 8);

  f32x16 oacc[4] = {};
  float mrow = -1e30f, lrow = 0.f;

  const int pbase = wave * 1024 + (lane << 4);   // 8KB per j-step, j in {0,1}

  auto stageK = [&](int buf, int tix) {
    const unsigned short* ksrc = Kh + hbase + (size_t)tix * (64 * HD);
#pragma unroll
    for (int j = 0; j < 2; ++j) {
      int p = pbase + j * 8192;
      int kr = p >> 8;                                   // row 0..63 (256B rows)
      int kc = ((p >> 4) & 15) ^ ((kr & 7) ^ ((kr >> 3) & 7));
      gll16(ksrc + kr * 128 + kc * 8, (char*)Ks + buf * 16384 + p);
    }
  };
  auto stageV = [&](int tix) {
    const unsigned short* vsrc = Vt + hbase + (size_t)tix * (64 * HD);
#pragma unroll
    for (int j = 0; j < 2; ++j) {
      int p = pbase + j * 8192;
      int vr = p >> 7;                                   // d-row 0..127 (128B rows)
      int vc = ((p >> 4) & 7) ^ (((vr & 7) ^ ((vr >> 3) & 7)) & 7);
      gll16(vsrc + vr * 64 + vc * 8, (char*)Vs + p);
    }
  };

  stageK(0, 0);   // 2 K-loads in flight

  const int NT = S_LEN / 64;
  for (int t = 0; t < NT; ++t) {
    const int cur = t & 1;
    stageV(t);                                          // +2 (V(t))
    stageK(cur ^ 1, (t + 1 < NT) ? t + 1 : t);          // +2 (K(t+1))
    asm volatile("s_waitcnt vmcnt(4)" ::: "memory");    // drain K(t) (oldest 2)
    __builtin_amdgcn_sched_barrier(0);
    __builtin_amdgcn_s_barrier();          // BAR1: K(t) visible to all waves
    __builtin_amdgcn_sched_barrier(0);

    // ---- QK^T swapped: pA = P[k=0..31][q], pB = P[k=32..63][q], q col = l31
    const char* kbp = (const char*)Ks + cur * 16384;
    const int fk0 = (l31 & 7) ^ ((l31 >> 3) & 7);            // f(row) for rows 0..31
    const int fk1 = (l31 & 7) ^ (((l31 + 32) >> 3) & 7);     // f(row+32)
    f32x16 pA = {}, pB = {};
    __builtin_amdgcn_s_setprio(1);
#pragma unroll
    for (int ds_ = 0; ds_ < 8; ++ds_) {
      bf16x8 k0 = *reinterpret_cast<const bf16x8*>(
          kbp + l31 * 256 + (((ds_ * 2 + hh) ^ fk0) << 4));
      bf16x8 k1 = *reinterpret_cast<const bf16x8*>(
          kbp + (32 + l31) * 256 + (((ds_ * 2 + hh) ^ fk1) << 4));
      pA = __builtin_amdgcn_mfma_f32_32x32x16_bf16(k0, qf[ds_], pA, 0, 0, 0);
      pB = __builtin_amdgcn_mfma_f32_32x32x16_bf16(k1, qf[ds_], pB, 0, 0, 0);
    }
    __builtin_amdgcn_s_setprio(0);

    // ---- online softmax (per-lane q-row = l31), tree reductions
    float m8[8];
#pragma unroll
    for (int r = 0; r < 8; ++r)
      m8[r] = fmaxf(fmaxf(pA[r], pA[r + 8]), fmaxf(pB[r], pB[r + 8]));
#pragma unroll
    for (int r = 0; r < 4; ++r) m8[r] = fmaxf(m8[r], m8[r + 4]);
    float mx = fmaxf(fmaxf(m8[0], m8[1]), fmaxf(m8[2], m8[3]));
    mx = fmaxf(mx, __shfl_xor(mx, 32));
    if (__any(mx > mrow + 8.0f)) {          // defer-max rescale (rare)
      float nm = fmaxf(mrow, mx);
      float alpha = exp2f(mrow - nm);
      mrow = nm;
      lrow *= alpha;
#pragma unroll
      for (int r = 0; r < 16; ++r) {
        int qr = (r & 3) + 8 * (r >> 2) + 4 * hh;
        float av = __shfl(alpha, qr);
        oacc[0][r] *= av; oacc[1][r] *= av; oacc[2][r] *= av; oacc[3][r] *= av;
      }
    }
#pragma unroll
    for (int r = 0; r < 16; ++r) pA[r] = exp2f(pA[r] - mrow);
#pragma unroll
    for (int r = 0; r < 16; ++r) pB[r] = exp2f(pB[r] - mrow);
    float s8[8];
#pragma unroll
    for (int r = 0; r < 8; ++r)
      s8[r] = (pA[r] + pA[r + 8]) + (pB[r] + pB[r + 8]);
#pragma unroll
    for (int r = 0; r < 4; ++r) s8[r] += s8[r + 4];
    lrow += (s8[0] + s8[1]) + (s8[2] + s8[3]);

    // ---- P -> bf16 A-frags in-register (cvt_pk + permlane32_swap)
    uint32_t w[16];
#pragma unroll
    for (int gg = 0; gg < 4; ++gg) {
      uint32_t lo, hi;
      float a0 = pA[4 * gg], a1 = pA[4 * gg + 1], a2 = pA[4 * gg + 2], a3 = pA[4 * gg + 3];
      asm("v_cvt_pk_bf16_f32 %0, %1, %2" : "=v"(lo) : "v"(a0), "v"(a1));
      asm("v_cvt_pk_bf16_f32 %0, %1, %2" : "=v"(hi) : "v"(a2), "v"(a3));
      w[gg * 2] = lo; w[gg * 2 + 1] = hi;
    }
#pragma unroll
    for (int gg = 0; gg < 4; ++gg) {
      uint32_t lo, hi;
      float a0 = pB[4 * gg], a1 = pB[4 * gg + 1], a2 = pB[4 * gg + 2], a3 = pB[4 * gg + 3];
      asm("v_cvt_pk_bf16_f32 %0, %1, %2" : "=v"(lo) : "v"(a0), "v"(a1));
      asm("v_cvt_pk_bf16_f32 %0, %1, %2" : "=v"(hi) : "v"(a2), "v"(a3));
      w[8 + gg * 2] = lo; w[8 + gg * 2 + 1] = hi;
    }
    bf16x8 pa[4];
#pragma unroll
    for (int s = 0; s < 4; ++s) {
      int wb = (s >> 1) * 8 + (s & 1) * 4;
      uint32_t le = w[wb], he = w[wb + 1], lo_ = w[wb + 2], ho = w[wb + 3];
      asm("v_permlane32_swap_b32 %0, %1" : "+v"(le), "+v"(lo_));
      asm("v_permlane32_swap_b32 %0, %1" : "+v"(he), "+v"(ho));
      u32x4 fr = {le, he, lo_, ho};
      pa[s] = __builtin_bit_cast(bf16x8, fr);
    }

    // ---- wait V(t) (drains to 2: K(t+1) stays in flight), then barrier
    asm volatile("s_waitcnt vmcnt(2)" ::: "memory");
    __builtin_amdgcn_sched_barrier(0);
    __builtin_amdgcn_s_barrier();          // BAR-mid: V(t) visible to all waves
    __builtin_amdgcn_sched_barrier(0);

    // ---- PV: O[q][d] += P[q][k] V[k][d]
    const char* vbp = (const char*)Vs;
    __builtin_amdgcn_s_setprio(1);
#pragma unroll
    for (int db = 0; db < 4; ++db) {
      int d = db * 32 + l31;
      int fv = (d & 7) ^ ((d >> 3) & 7);
#pragma unroll
      for (int ks = 0; ks < 4; ++ks) {
        bf16x8 vv = *reinterpret_cast<const bf16x8*>(
            vbp + d * 128 + (((ks * 2 + hh) ^ fv) << 4));
        oacc[db] = __builtin_amdgcn_mfma_f32_32x32x16_bf16(pa[ks], vv, oacc[db], 0, 0, 0);
      }
    }
    __builtin_amdgcn_s_setprio(0);

    __builtin_amdgcn_sched_barrier(0);
    __builtin_amdgcn_s_barrier();          // BAR2: Vs + Ks[cur] reads done
    __builtin_amdgcn_sched_barrier(0);
  }

  // ---- epilogue: reduce l across halves, normalize, store
  lrow += __shfl_xor(lrow, 32);
  float inv_[16];
#pragma unroll
  for (int r = 0; r < 16; ++r) {
    int qr = (r & 3) + 8 * (r >> 2) + 4 * hh;
    inv_[r] = 1.0f / __shfl(lrow, qr);
  }
#pragma unroll
  for (int db = 0; db < 4; ++db) {
#pragma unroll
    for (int r = 0; r < 16; ++r) {
      int qr = (r & 3) + 8 * (r >> 2) + 4 * hh;
      O[qbase + (size_t)(q0w + qr) * D_DIM + db * 32 + l31] =
          f2bf(oacc[db][r] * inv_[r]);
    }
  }
}

// ---------------- launch ----------------
extern "C" void kernel_launch(void* const* d_in, const int* in_sizes, int n_in,
                              void* d_out, int out_size, void* d_ws, size_t ws_size,
                              hipStream_t stream) {
  const float* x   = (const float*)d_in[0];
  const float* fc  = (const float*)d_in[1];
  const float* fs  = (const float*)d_in[2];
  const float* qw  = (const float*)d_in[3];
  const float* qb  = (const float*)d_in[4];
  const float* kw  = (const float*)d_in[5];
  const float* kb  = (const float*)d_in[6];
  const float* vw  = (const float*)d_in[7];
  const float* vb  = (const float*)d_in[8];
  const float* ow  = (const float*)d_in[9];
  const float* ob  = (const float*)d_in[10];
  const float* qnw = (const float*)d_in[11];
  const float* knw = (const float*)d_in[12];
  float* out = (float*)d_out;

  const size_t MSD = (size_t)MROWS * D_DIM;
  const size_t WSZ = (size_t)D_DIM * D_DIM;
  char* ws = (char*)d_ws;
  unsigned short* xb   = (unsigned short*)ws; ws += MSD * 2;
  unsigned short* qwb  = (unsigned short*)ws; ws += WSZ * 2;   // qwb,kwb,vwb contiguous
  unsigned short* kwb  = (unsigned short*)ws; ws += WSZ * 2;   //   = Bt[6144][2048]
  unsigned short* vwb  = (unsigned short*)ws; ws += WSZ * 2;
  unsigned short* owb  = (unsigned short*)ws; ws += WSZ * 2;
  float*          cbias = (float*)ws;         ws += 3 * D_DIM * 4;
  unsigned short* qpre = (unsigned short*)ws; ws += MSD * 2;   // bf16 pre-norm Q
  unsigned short* kpre = (unsigned short*)ws; ws += MSD * 2;   // bf16 pre-norm K
  unsigned short* qb16 = (unsigned short*)ws; ws += MSD * 2;
  unsigned short* kb16 = (unsigned short*)ws; ws += MSD * 2;   // Kh[b][h][s][d]
  unsigned short* vt16 = (unsigned short*)ws; ws += MSD * 2;   // Vt2[b][h][s/64][d][s%64]
  unsigned short* ob16 = (unsigned short*)ws; ws += MSD * 2;

  cast_all<<<2048, 256, 0, stream>>>(x, qw, kw, vw, ow, xb, qwb, kwb, vwb, owb);
  hipMemcpyAsync(cbias,              qb, D_DIM * sizeof(float), hipMemcpyDeviceToDevice, stream);
  hipMemcpyAsync(cbias + D_DIM,      kb, D_DIM * sizeof(float), hipMemcpyDeviceToDevice, stream);
  hipMemcpyAsync(cbias + 2 * D_DIM,  vb, D_DIM * sizeof(float), hipMemcpyDeviceToDevice, stream);

  // fused QKV projection: M=4096, N=6144, K=2048 -> 768 blocks (3 full CU-waves)
  gemm256<3><<<dim3((MROWS / 128) * (3 * D_DIM / 256)), 512, 0, stream>>>(
      xb, qwb, cbias, qpre, kpre, vt16, MROWS, 3 * D_DIM, D_DIM);

  const float qscale = 0.08838834764831845f * 1.4426950408889634f;
  norm_rope<0><<<MROWS, 256, 0, stream>>>(qpre, qnw, fc, fs, qb16, qscale);
  norm_rope<1><<<MROWS, 256, 0, stream>>>(kpre, knw, fc, fs, kb16, 1.0f);

  attn_kernel<<<dim3(S_LEN / 256 * NHEAD * B_SZ), 512, 0, stream>>>(qb16, kb16, vt16, ob16);

  // output projection: M=4096, N=2048 -> 256 blocks (1/CU)
  gemm256<0><<<dim3((MROWS / 128) * (D_DIM / 256)), 512, 0, stream>>>(
      ob16, owb, ob, out, nullptr, nullptr, MROWS, D_DIM, D_DIM);
}

// Round 13
// 324.340 us; speedup vs baseline: 1.1266x; 1.1266x over previous
//
#include <hip/hip_runtime.h>
#include <stdint.h>

#define B_SZ 2
#define S_LEN 2048
#define D_DIM 2048
#define NHEAD 16
#define HD 128
#define HALF 64
#define MROWS (B_SZ * S_LEN)   // 4096

typedef __attribute__((ext_vector_type(8))) __bf16 bf16x8;
typedef __attribute__((ext_vector_type(8))) unsigned short u16x8;
typedef __attribute__((ext_vector_type(4))) float f32x4;
typedef __attribute__((ext_vector_type(16))) float f32x16;
typedef __attribute__((ext_vector_type(4))) unsigned int u32x4;

__device__ inline unsigned short f2bf(float x) {
  union { float f; uint32_t u; } c; c.f = x;
  uint32_t r = (c.u + 0x7fffu + ((c.u >> 16) & 1u)) >> 16;
  return (unsigned short)r;
}

__device__ inline float bf2f(unsigned short b) {
  union { uint32_t u; float f; } c; c.u = (uint32_t)b << 16;
  return c.f;
}

__device__ inline void gll16(const void* g, void* l) {
  __builtin_amdgcn_global_load_lds(
      (const __attribute__((address_space(1))) void*)g,
      (__attribute__((address_space(3))) void*)l,
      16, 0, 0);
}

// ---------------- fused cast f32 -> bf16 for x + 4 weight matrices ----------------
__global__ void cast_all(const float* __restrict__ x,
                         const float* __restrict__ qw, const float* __restrict__ kw,
                         const float* __restrict__ vw, const float* __restrict__ ow,
                         unsigned short* __restrict__ xb,
                         unsigned short* __restrict__ qwb, unsigned short* __restrict__ kwb,
                         unsigned short* __restrict__ vwb, unsigned short* __restrict__ owb) {
  const int n_x = (MROWS * D_DIM) / 4;
  const int n_w = (D_DIM * D_DIM) / 4;      // == 1<<20
  const int total = n_x + 4 * n_w;
  int i = blockIdx.x * blockDim.x + threadIdx.x;
  int stride = gridDim.x * blockDim.x;
  for (; i < total; i += stride) {
    const float* src; unsigned short* dst; int off;
    if (i < n_x) { src = x; dst = xb; off = i; }
    else {
      int j = i - n_x;
      int seg = j >> 20;
      off = j & (n_w - 1);
      src = seg == 0 ? qw : seg == 1 ? kw : seg == 2 ? vw : ow;
      dst = seg == 0 ? qwb : seg == 1 ? kwb : seg == 2 ? vwb : owb;
    }
    float4 v = reinterpret_cast<const float4*>(src)[off];
    ushort4 o;
    o.x = f2bf(v.x); o.y = f2bf(v.y); o.z = f2bf(v.z); o.w = f2bf(v.w);
    reinterpret_cast<ushort4*>(dst)[off] = o;
  }
}

// ---------------- GEMM 128x128 tile, BK=32, 4 waves (PROVEN m97 structure) ----------------
// C[i,j] = sum_k A[i,k]*Bt[j,k] + bias[j].
// MODE 0: fp32 linear out -> C0.
// MODE 3: QKV fused (N=6144): seg0 -> (ushort*)C0 bf16 linear, seg1 -> C1 bf16
//         linear, seg2 -> C2 = Vt2[b][h][s/64][d][s%64].
// 256 thr, 16KB LDS -> ~4 blocks/CU = 16 waves/CU (round-12 lesson: this TLP
// beats the 512-thr/144KB phase-scheduled variant by ~1.5x).
template <int MODE>
__global__ __launch_bounds__(256) void gemm_bt(
    const unsigned short* __restrict__ A, const unsigned short* __restrict__ Bt,
    const float* __restrict__ bias, void* __restrict__ C0,
    unsigned short* __restrict__ C1, unsigned short* __restrict__ C2,
    int M, int N, int K) {
  __shared__ __align__(16) unsigned short As[128 * 32];
  __shared__ __align__(16) unsigned short Bs[128 * 32];
  const int tid = threadIdx.x;
  const int lane = tid & 63;
  const int wave = tid >> 6;
  const int nbn = N >> 7;
  const int chunk = gridDim.x >> 3;
  const int lin = (blockIdx.x & 7) * chunk + (blockIdx.x >> 3);
  const int bm = lin / nbn, bn = lin - bm * nbn;
  const int wr = wave >> 1, wc = wave & 1;
  const int lm = lane & 15, lg = lane >> 4;

  f32x4 acc[4][4] = {};

  for (int k0 = 0; k0 < K; k0 += 32) {
    __syncthreads();
#pragma unroll
    for (int j = 0; j < 2; ++j) {
      int ob = wave * 2048 + j * 1024;
      int o = ob + lane * 16;
      int row = o >> 6;
      int col = (o & 63) >> 1;
      const unsigned short* ga = A + (size_t)(bm * 128 + row) * K + k0 + col;
      gll16(ga, (char*)As + ob);
      const unsigned short* gb = Bt + (size_t)(bn * 128 + row) * K + k0 + col;
      gll16(gb, (char*)Bs + ob);
    }
    __syncthreads();

    bf16x8 af[4], bfr[4];
#pragma unroll
    for (int mi = 0; mi < 4; ++mi)
      af[mi] = *reinterpret_cast<const bf16x8*>(
          &As[(wr * 64 + mi * 16 + lm) * 32 + lg * 8]);
#pragma unroll
    for (int ni = 0; ni < 4; ++ni)
      bfr[ni] = *reinterpret_cast<const bf16x8*>(
          &Bs[(wc * 64 + ni * 16 + lm) * 32 + lg * 8]);
#pragma unroll
    for (int mi = 0; mi < 4; ++mi)
#pragma unroll
      for (int ni = 0; ni < 4; ++ni)
        acc[mi][ni] = __builtin_amdgcn_mfma_f32_16x16x32_bf16(
            af[mi], bfr[ni], acc[mi][ni], 0, 0, 0);
  }

#pragma unroll
  for (int ni = 0; ni < 4; ++ni) {
    int col = bn * 128 + wc * 64 + ni * 16 + lm;
    float bv = bias[col];
    if constexpr (MODE == 3) {
      int seg = col >> 11;            // 0=Q, 1=K, 2=V
      int c2 = col & (D_DIM - 1);
#pragma unroll
      for (int mi = 0; mi < 4; ++mi) {
        int row0 = bm * 128 + wr * 64 + mi * 16 + lg * 4;
        if (seg == 2) {
          int b = row0 >> 11, s0 = row0 & (S_LEN - 1);
          int h = c2 >> 7, d = c2 & (HD - 1);
          ushort4 o;
          o.x = f2bf(acc[mi][ni][0] + bv);
          o.y = f2bf(acc[mi][ni][1] + bv);
          o.z = f2bf(acc[mi][ni][2] + bv);
          o.w = f2bf(acc[mi][ni][3] + bv);
          size_t oi = ((((size_t)(b * NHEAD + h) * (S_LEN / 64) + (s0 >> 6)) * HD + d) << 6)
                      + (s0 & 63);
          *reinterpret_cast<ushort4*>(C2 + oi) = o;
        } else {
          unsigned short* dst = (seg == 0) ? (unsigned short*)C0 : C1;
#pragma unroll
          for (int r = 0; r < 4; ++r)
            dst[(size_t)(row0 + r) * D_DIM + c2] = f2bf(acc[mi][ni][r] + bv);
        }
      }
    } else {
      float* out = (float*)C0;
#pragma unroll
      for (int mi = 0; mi < 4; ++mi) {
        int row0 = bm * 128 + wr * 64 + mi * 16 + lg * 4;
#pragma unroll
        for (int r = 0; r < 4; ++r)
          out[(size_t)(row0 + r) * N + col] = acc[mi][ni][r] + bv;
      }
    }
  }
}

// ---------------- merged RMSNorm+RoPE for Q (linear out) and K (head-blocked out) ----------------
__global__ __launch_bounds__(256) void norm_rope2(
    const unsigned short* __restrict__ qin, const unsigned short* __restrict__ kin,
    const float* __restrict__ qnw, const float* __restrict__ knw,
    const float* __restrict__ cosb, const float* __restrict__ sinb,
    unsigned short* __restrict__ qout, unsigned short* __restrict__ kout,
    float qscale) {
  const int isK = blockIdx.x >> 12;                // grid = 2*MROWS
  const int row = blockIdx.x & (MROWS - 1);
  const int pos = row & (S_LEN - 1);
  const unsigned short* hr = (isK ? kin : qin) + (size_t)row * D_DIM;
  const float* w = isK ? knw : qnw;
  const float outscale = isK ? 1.0f : qscale;
  const int t = threadIdx.x;
  const int d = t * 8;

  u16x8 hv = *reinterpret_cast<const u16x8*>(hr + d);
  float a[8];
#pragma unroll
  for (int i = 0; i < 8; ++i) a[i] = bf2f(hv[i]);
  float ss = 0.f;
#pragma unroll
  for (int i = 0; i < 8; ++i) ss += a[i] * a[i];
#pragma unroll
  for (int off = 32; off > 0; off >>= 1) ss += __shfl_down(ss, off);
  __shared__ float red[4];
  if ((t & 63) == 0) red[t >> 6] = ss;
  __syncthreads();
  float tot = red[0] + red[1] + red[2] + red[3];
  float inv = rsqrtf(tot * (1.0f / D_DIM) + 1e-6f) * outscale;

  const int p = (d & (HD - 1)) >> 1;
  const float* cp = cosb + pos * HALF + p;
  const float* sp = sinb + pos * HALF + p;
  const float* wp = w + d;

  float c0 = cp[0], c1 = cp[1], c2 = cp[2], c3 = cp[3];
  float s0 = sp[0], s1 = sp[1], s2 = sp[2], s3 = sp[3];
#pragma unroll
  for (int i = 0; i < 8; ++i) a[i] = a[i] * inv * wp[i];
  u16x8 o;
  o[0] = f2bf(a[0] * c0 - a[1] * s0);
  o[1] = f2bf(a[0] * s0 + a[1] * c0);
  o[2] = f2bf(a[2] * c1 - a[3] * s1);
  o[3] = f2bf(a[2] * s1 + a[3] * c1);
  o[4] = f2bf(a[4] * c2 - a[5] * s2);
  o[5] = f2bf(a[4] * s2 + a[5] * c2);
  o[6] = f2bf(a[6] * c3 - a[7] * s3);
  o[7] = f2bf(a[6] * s3 + a[7] * c3);
  if (isK) {
    int hh = t >> 4;
    int dd = d & (HD - 1);
    size_t oi = (((size_t)((row >> 11) * NHEAD + hh) * S_LEN) + pos) * HD + dd;
    *reinterpret_cast<u16x8*>(kout + oi) = o;
  } else {
    *reinterpret_cast<u16x8*>(qout + (size_t)row * D_DIM + d) = o;
  }
}

// ---------------- flash attention: 8 waves x 32q (QBLK=256), KVBLK=128 ----------------
// grid = 256 = 1 block/CU; K dbuf 2x32KB + V single 32KB = 96KB LDS.
// KVBLK 64->128: halves barrier rounds (32->16) and per-tile fixed costs.
// Per tile: stageV(t) +4, stageK(t+1) +4; vmcnt(8) drains K(t); after
// QK+softmax vmcnt(4) drains V(t), K(t+1) stays in flight; 3 barriers/tile.
// Full-rank XOR swizzle f(r)=(r&7)^((r>>3)&7) on stage-source AND read.
// Swapped QK^T; tree softmax; in-register P (cvt_pk+permlane); defer-max THR=8.
__global__ __launch_bounds__(512) void attn_kernel(
    const unsigned short* __restrict__ Q, const unsigned short* __restrict__ Kh,
    const unsigned short* __restrict__ Vt, unsigned short* __restrict__ O) {
  const int idx = blockIdx.x;
  const int swz = (idx & 7) * 32 + (idx >> 3);   // 256 blocks, 32/XCD (4 heads)
  const int qb = swz & 7;
  const int h = (swz >> 3) & 15;
  const int b = swz >> 7;

  const int tid = threadIdx.x;
  const int lane = tid & 63;
  const int wave = tid >> 6;          // 0..7
  const int l31 = lane & 31;
  const int hh = lane >> 5;

  const size_t qbase = (size_t)b * S_LEN * D_DIM + (size_t)h * HD;   // linear Q/O
  const size_t hbase = (size_t)(b * NHEAD + h) * S_LEN * HD;         // blocked K/V
  const int q0w = qb * 256 + wave * 32;

  __shared__ __align__(16) unsigned short Ks[2 * 128 * 128];  // 2 x 32KB (dbuf)
  __shared__ __align__(16) unsigned short Vs[2 * 128 * 64];   // 32KB (2 s-halves)

  bf16x8 qf[8];
#pragma unroll
  for (int ds_ = 0; ds_ < 8; ++ds_)
    qf[ds_] = *reinterpret_cast<const bf16x8*>(
        Q + qbase + (size_t)(q0w + l31) * D_DIM + ds_ * 16 + hh * 8);

  f32x16 oacc[4] = {};
  float mrow = -1e30f, lrow = 0.f;

  const int pbase = wave * 1024 + (lane << 4);   // + j*8192, j=0..3 -> [0,32768)

  auto stageK = [&](int buf, int tix) {
    const unsigned short* ksrc = Kh + hbase + (size_t)tix * (128 * HD);
#pragma unroll
    for (int j = 0; j < 4; ++j) {
      int p = pbase + j * 8192;
      int kr = p >> 8;                                   // row 0..127 (256B rows)
      int kc = ((p >> 4) & 15) ^ ((kr & 7) ^ ((kr >> 3) & 7));
      gll16(ksrc + kr * 128 + kc * 8, (char*)Ks + buf * 32768 + p);
    }
  };
  auto stageV = [&](int tix) {
    const unsigned short* vsrc = Vt + hbase + (size_t)tix * (128 * HD);  // 2 v-tiles
#pragma unroll
    for (int j = 0; j < 4; ++j) {
      int p = pbase + j * 8192;
      int vr = (p & 16383) >> 7;                         // d-row 0..127 (128B rows)
      int vc = ((p >> 4) & 7) ^ (((vr & 7) ^ ((vr >> 3) & 7)) & 7);
      gll16(vsrc + (p >> 14) * (64 * HD) + vr * 64 + vc * 8, (char*)Vs + p);
    }
  };

  stageK(0, 0);   // 4 K-loads in flight

  const int NT = S_LEN / 128;          // 16
  for (int t = 0; t < NT; ++t) {
    const int cur = t & 1;
    stageV(t);                                          // +4 (V(t))
    stageK(cur ^ 1, (t + 1 < NT) ? t + 1 : t);          // +4 (K(t+1))
    asm volatile("s_waitcnt vmcnt(8)" ::: "memory");    // drain K(t) (oldest 4)
    __builtin_amdgcn_sched_barrier(0);
    __builtin_amdgcn_s_barrier();          // BAR1: K(t) visible
    __builtin_amdgcn_sched_barrier(0);

    // ---- QK^T swapped: sc[j] = P[k = 32j..32j+31][q = l31]
    const char* kbp = (const char*)Ks + cur * 32768;
    f32x16 sc[4] = {};
    __builtin_amdgcn_s_setprio(1);
#pragma unroll
    for (int ds_ = 0; ds_ < 8; ++ds_) {
#pragma unroll
      for (int j = 0; j < 4; ++j) {
        int r = j * 32 + l31;
        bf16x8 kf = *reinterpret_cast<const bf16x8*>(
            kbp + r * 256 + (((ds_ * 2 + hh) ^ ((r & 7) ^ ((r >> 3) & 7))) << 4));
        sc[j] = __builtin_amdgcn_mfma_f32_32x32x16_bf16(kf, qf[ds_], sc[j], 0, 0, 0);
      }
    }
    __builtin_amdgcn_s_setprio(0);

    // ---- online softmax (per-lane q-row = l31), tree reductions over 64 vals
    float m0[16];
#pragma unroll
    for (int r = 0; r < 16; ++r)
      m0[r] = fmaxf(fmaxf(sc[0][r], sc[1][r]), fmaxf(sc[2][r], sc[3][r]));
#pragma unroll
    for (int r = 0; r < 8; ++r) m0[r] = fmaxf(m0[r], m0[r + 8]);
#pragma unroll
    for (int r = 0; r < 4; ++r) m0[r] = fmaxf(m0[r], m0[r + 4]);
    float mx = fmaxf(fmaxf(m0[0], m0[1]), fmaxf(m0[2], m0[3]));
    mx = fmaxf(mx, __shfl_xor(mx, 32));
    if (__any(mx > mrow + 8.0f)) {          // defer-max rescale (rare)
      float nm = fmaxf(mrow, mx);
      float alpha = exp2f(mrow - nm);
      mrow = nm;
      lrow *= alpha;
#pragma unroll
      for (int r = 0; r < 16; ++r) {
        int qr = (r & 3) + 8 * (r >> 2) + 4 * hh;
        float av = __shfl(alpha, qr);
        oacc[0][r] *= av; oacc[1][r] *= av; oacc[2][r] *= av; oacc[3][r] *= av;
      }
    }
#pragma unroll
    for (int j = 0; j < 4; ++j)
#pragma unroll
      for (int r = 0; r < 16; ++r) sc[j][r] = exp2f(sc[j][r] - mrow);
    float s0[16];
#pragma unroll
    for (int r = 0; r < 16; ++r)
      s0[r] = (sc[0][r] + sc[1][r]) + (sc[2][r] + sc[3][r]);
#pragma unroll
    for (int r = 0; r < 8; ++r) s0[r] += s0[r + 8];
#pragma unroll
    for (int r = 0; r < 4; ++r) s0[r] += s0[r + 4];
    lrow += (s0[0] + s0[1]) + (s0[2] + s0[3]);

    // ---- P -> bf16 A-frags in-register (cvt_pk + permlane32_swap)
    uint32_t w[32];
#pragma unroll
    for (int X = 0; X < 4; ++X) {
#pragma unroll
      for (int g = 0; g < 4; ++g) {
        uint32_t lo, hi;
        float a0 = sc[X][4 * g], a1 = sc[X][4 * g + 1];
        float a2 = sc[X][4 * g + 2], a3 = sc[X][4 * g + 3];
        asm("v_cvt_pk_bf16_f32 %0, %1, %2" : "=v"(lo) : "v"(a0), "v"(a1));
        asm("v_cvt_pk_bf16_f32 %0, %1, %2" : "=v"(hi) : "v"(a2), "v"(a3));
        w[X * 8 + g * 2] = lo; w[X * 8 + g * 2 + 1] = hi;
      }
    }
    bf16x8 pa[8];
#pragma unroll
    for (int s = 0; s < 8; ++s) {
      int wb = (s >> 1) * 8 + (s & 1) * 4;
      uint32_t le = w[wb], he = w[wb + 1], lo_ = w[wb + 2], ho = w[wb + 3];
      asm("v_permlane32_swap_b32 %0, %1" : "+v"(le), "+v"(lo_));
      asm("v_permlane32_swap_b32 %0, %1" : "+v"(he), "+v"(ho));
      u32x4 fr = {le, he, lo_, ho};
      pa[s] = __builtin_bit_cast(bf16x8, fr);
    }

    // ---- wait V(t) (drains to 4: K(t+1) stays in flight), then barrier
    asm volatile("s_waitcnt vmcnt(4)" ::: "memory");
    __builtin_amdgcn_sched_barrier(0);
    __builtin_amdgcn_s_barrier();          // BAR-mid: V(t) visible
    __builtin_amdgcn_sched_barrier(0);

    // ---- PV: O[q][d] += P[q][k] V[k][d], k 0..127 in 8 slots
    const char* vbp = (const char*)Vs;
    __builtin_amdgcn_s_setprio(1);
#pragma unroll
    for (int db = 0; db < 4; ++db) {
      int d = db * 32 + l31;
      int fv = ((d & 7) ^ ((d >> 3) & 7)) & 7;
#pragma unroll
      for (int ks = 0; ks < 8; ++ks) {
        bf16x8 vv = *reinterpret_cast<const bf16x8*>(
            vbp + (ks >> 2) * 16384 + d * 128 + ((((ks & 3) * 2 + hh) ^ fv) << 4));
        oacc[db] = __builtin_amdgcn_mfma_f32_32x32x16_bf16(pa[ks], vv, oacc[db], 0, 0, 0);
      }
    }
    __builtin_amdgcn_s_setprio(0);

    __builtin_amdgcn_sched_barrier(0);
    __builtin_amdgcn_s_barrier();          // BAR2: Vs + Ks[cur] reads done
    __builtin_amdgcn_sched_barrier(0);
  }

  // ---- epilogue: reduce l across halves, normalize, store
  lrow += __shfl_xor(lrow, 32);
  float inv_[16];
#pragma unroll
  for (int r = 0; r < 16; ++r) {
    int qr = (r & 3) + 8 * (r >> 2) + 4 * hh;
    inv_[r] = 1.0f / __shfl(lrow, qr);
  }
#pragma unroll
  for (int db = 0; db < 4; ++db) {
#pragma unroll
    for (int r = 0; r < 16; ++r) {
      int qr = (r & 3) + 8 * (r >> 2) + 4 * hh;
      O[qbase + (size_t)(q0w + qr) * D_DIM + db * 32 + l31] =
          f2bf(oacc[db][r] * inv_[r]);
    }
  }
}

// ---------------- launch ----------------
extern "C" void kernel_launch(void* const* d_in, const int* in_sizes, int n_in,
                              void* d_out, int out_size, void* d_ws, size_t ws_size,
                              hipStream_t stream) {
  const float* x   = (const float*)d_in[0];
  const float* fc  = (const float*)d_in[1];
  const float* fs  = (const float*)d_in[2];
  const float* qw  = (const float*)d_in[3];
  const float* qb  = (const float*)d_in[4];
  const float* kw  = (const float*)d_in[5];
  const float* kb  = (const float*)d_in[6];
  const float* vw  = (const float*)d_in[7];
  const float* vb  = (const float*)d_in[8];
  const float* ow  = (const float*)d_in[9];
  const float* ob  = (const float*)d_in[10];
  const float* qnw = (const float*)d_in[11];
  const float* knw = (const float*)d_in[12];
  float* out = (float*)d_out;

  const size_t MSD = (size_t)MROWS * D_DIM;
  const size_t WSZ = (size_t)D_DIM * D_DIM;
  char* ws = (char*)d_ws;
  unsigned short* xb   = (unsigned short*)ws; ws += MSD * 2;
  unsigned short* qwb  = (unsigned short*)ws; ws += WSZ * 2;   // qwb,kwb,vwb contiguous
  unsigned short* kwb  = (unsigned short*)ws; ws += WSZ * 2;   //   = Bt[6144][2048]
  unsigned short* vwb  = (unsigned short*)ws; ws += WSZ * 2;
  unsigned short* owb  = (unsigned short*)ws; ws += WSZ * 2;
  float*          cbias = (float*)ws;         ws += 3 * D_DIM * 4;
  unsigned short* qpre = (unsigned short*)ws; ws += MSD * 2;   // bf16 pre-norm Q
  unsigned short* kpre = (unsigned short*)ws; ws += MSD * 2;   // bf16 pre-norm K
  unsigned short* qb16 = (unsigned short*)ws; ws += MSD * 2;
  unsigned short* kb16 = (unsigned short*)ws; ws += MSD * 2;   // Kh[b][h][s][d]
  unsigned short* vt16 = (unsigned short*)ws; ws += MSD * 2;   // Vt2[b][h][s/64][d][s%64]
  unsigned short* ob16 = (unsigned short*)ws; ws += MSD * 2;

  cast_all<<<2048, 256, 0, stream>>>(x, qw, kw, vw, ow, xb, qwb, kwb, vwb, owb);
  hipMemcpyAsync(cbias,              qb, D_DIM * sizeof(float), hipMemcpyDeviceToDevice, stream);
  hipMemcpyAsync(cbias + D_DIM,      kb, D_DIM * sizeof(float), hipMemcpyDeviceToDevice, stream);
  hipMemcpyAsync(cbias + 2 * D_DIM,  vb, D_DIM * sizeof(float), hipMemcpyDeviceToDevice, stream);

  // fused QKV projection: M=4096, N=6144, K=2048 -> 1536 blocks (~4/CU)
  gemm_bt<3><<<dim3((MROWS / 128) * (3 * D_DIM / 128)), 256, 0, stream>>>(
      xb, qwb, cbias, qpre, kpre, vt16, MROWS, 3 * D_DIM, D_DIM);

  const float qscale = 0.08838834764831845f * 1.4426950408889634f;
  norm_rope2<<<2 * MROWS, 256, 0, stream>>>(qpre, kpre, qnw, knw, fc, fs,
                                            qb16, kb16, qscale);

  attn_kernel<<<dim3(S_LEN / 256 * NHEAD * B_SZ), 512, 0, stream>>>(qb16, kb16, vt16, ob16);

  // output projection: M=4096, N=2048 -> 512 blocks
  gemm_bt<0><<<dim3((MROWS / 128) * (D_DIM / 128)), 256, 0, stream>>>(
      ob16, owb, ob, out, nullptr, nullptr, MROWS, D_DIM, D_DIM);
}

// Round 14
// 322.977 us; speedup vs baseline: 1.1313x; 1.0042x over previous
//
#include <hip/hip_runtime.h>
#include <stdint.h>

#define B_SZ 2
#define S_LEN 2048
#define D_DIM 2048
#define NHEAD 16
#define HD 128
#define HALF 64
#define MROWS (B_SZ * S_LEN)   // 4096

typedef __attribute__((ext_vector_type(8))) __bf16 bf16x8;
typedef __attribute__((ext_vector_type(8))) unsigned short u16x8;
typedef __attribute__((ext_vector_type(4))) float f32x4;
typedef __attribute__((ext_vector_type(16))) float f32x16;
typedef __attribute__((ext_vector_type(4))) unsigned int u32x4;

__device__ inline unsigned short f2bf(float x) {
  union { float f; uint32_t u; } c; c.f = x;
  uint32_t r = (c.u + 0x7fffu + ((c.u >> 16) & 1u)) >> 16;
  return (unsigned short)r;
}

__device__ inline float bf2f(unsigned short b) {
  union { uint32_t u; float f; } c; c.u = (uint32_t)b << 16;
  return c.f;
}

__device__ inline void gll16(const void* g, void* l) {
  __builtin_amdgcn_global_load_lds(
      (const __attribute__((address_space(1))) void*)g,
      (__attribute__((address_space(3))) void*)l,
      16, 0, 0);
}

// ---------------- fused cast f32 -> bf16 for x + 4 weight matrices ----------------
__global__ void cast_all(const float* __restrict__ x,
                         const float* __restrict__ qw, const float* __restrict__ kw,
                         const float* __restrict__ vw, const float* __restrict__ ow,
                         unsigned short* __restrict__ xb,
                         unsigned short* __restrict__ qwb, unsigned short* __restrict__ kwb,
                         unsigned short* __restrict__ vwb, unsigned short* __restrict__ owb) {
  const int n_x = (MROWS * D_DIM) / 4;
  const int n_w = (D_DIM * D_DIM) / 4;      // == 1<<20
  const int total = n_x + 4 * n_w;
  int i = blockIdx.x * blockDim.x + threadIdx.x;
  int stride = gridDim.x * blockDim.x;
  for (; i < total; i += stride) {
    const float* src; unsigned short* dst; int off;
    if (i < n_x) { src = x; dst = xb; off = i; }
    else {
      int j = i - n_x;
      int seg = j >> 20;
      off = j & (n_w - 1);
      src = seg == 0 ? qw : seg == 1 ? kw : seg == 2 ? vw : ow;
      dst = seg == 0 ? qwb : seg == 1 ? kwb : seg == 2 ? vwb : owb;
    }
    float4 v = reinterpret_cast<const float4*>(src)[off];
    ushort4 o;
    o.x = f2bf(v.x); o.y = f2bf(v.y); o.z = f2bf(v.z); o.w = f2bf(v.w);
    reinterpret_cast<ushort4*>(dst)[off] = o;
  }
}

// ---------------- GEMM 128x128 tile, BK=32, 4 waves (PROVEN m97 structure) ----------------
// C[i,j] = sum_k A[i,k]*Bt[j,k] + bias[j].
// bn-MAJOR XCD chunk map (round-13 lesson: row-major map re-fetched B per
// bm-row -> 287MB HBM, time == FETCH/BW). Here each XCD owns nbn/8 B panels
// (<=3MB, L2-resident, fetched once); all 8 XCDs stream the SAME A panels
// concurrently -> A stays L3-hot -> HBM ~ A once + B once.
// MODE 0: fp32 linear out -> C0.
// MODE 3: QKV fused (N=6144): seg0 -> (ushort*)C0 bf16 linear, seg1 -> C1 bf16
//         linear, seg2 -> C2 = Vt2[b][h][s/64][d][s%64].
template <int MODE>
__global__ __launch_bounds__(256) void gemm_bt(
    const unsigned short* __restrict__ A, const unsigned short* __restrict__ Bt,
    const float* __restrict__ bias, void* __restrict__ C0,
    unsigned short* __restrict__ C1, unsigned short* __restrict__ C2,
    int M, int N, int K) {
  __shared__ __align__(16) unsigned short As[128 * 32];
  __shared__ __align__(16) unsigned short Bs[128 * 32];
  const int tid = threadIdx.x;
  const int lane = tid & 63;
  const int wave = tid >> 6;
  const int nbn = N >> 7;
  const int xcd = blockIdx.x & 7;
  const int w = blockIdx.x >> 3;        // 0..chunk-1, chunk = 32*(nbn/8)
  const int bm = w & 31;                // M = 4096 -> 32 bm panels
  const int bn = xcd * (nbn >> 3) + (w >> 5);
  const int wr = wave >> 1, wc = wave & 1;
  const int lm = lane & 15, lg = lane >> 4;

  f32x4 acc[4][4] = {};

  for (int k0 = 0; k0 < K; k0 += 32) {
    __syncthreads();
#pragma unroll
    for (int j = 0; j < 2; ++j) {
      int ob = wave * 2048 + j * 1024;
      int o = ob + lane * 16;
      int row = o >> 6;
      int col = (o & 63) >> 1;
      const unsigned short* ga = A + (size_t)(bm * 128 + row) * K + k0 + col;
      gll16(ga, (char*)As + ob);
      const unsigned short* gb = Bt + (size_t)(bn * 128 + row) * K + k0 + col;
      gll16(gb, (char*)Bs + ob);
    }
    __syncthreads();

    bf16x8 af[4], bfr[4];
#pragma unroll
    for (int mi = 0; mi < 4; ++mi)
      af[mi] = *reinterpret_cast<const bf16x8*>(
          &As[(wr * 64 + mi * 16 + lm) * 32 + lg * 8]);
#pragma unroll
    for (int ni = 0; ni < 4; ++ni)
      bfr[ni] = *reinterpret_cast<const bf16x8*>(
          &Bs[(wc * 64 + ni * 16 + lm) * 32 + lg * 8]);
#pragma unroll
    for (int mi = 0; mi < 4; ++mi)
#pragma unroll
      for (int ni = 0; ni < 4; ++ni)
        acc[mi][ni] = __builtin_amdgcn_mfma_f32_16x16x32_bf16(
            af[mi], bfr[ni], acc[mi][ni], 0, 0, 0);
  }

#pragma unroll
  for (int ni = 0; ni < 4; ++ni) {
    int col = bn * 128 + wc * 64 + ni * 16 + lm;
    float bv = bias[col];
    if constexpr (MODE == 3) {
      int seg = col >> 11;            // 0=Q, 1=K, 2=V
      int c2 = col & (D_DIM - 1);
#pragma unroll
      for (int mi = 0; mi < 4; ++mi) {
        int row0 = bm * 128 + wr * 64 + mi * 16 + lg * 4;
        if (seg == 2) {
          int b = row0 >> 11, s0 = row0 & (S_LEN - 1);
          int h = c2 >> 7, d = c2 & (HD - 1);
          ushort4 o;
          o.x = f2bf(acc[mi][ni][0] + bv);
          o.y = f2bf(acc[mi][ni][1] + bv);
          o.z = f2bf(acc[mi][ni][2] + bv);
          o.w = f2bf(acc[mi][ni][3] + bv);
          size_t oi = ((((size_t)(b * NHEAD + h) * (S_LEN / 64) + (s0 >> 6)) * HD + d) << 6)
                      + (s0 & 63);
          *reinterpret_cast<ushort4*>(C2 + oi) = o;
        } else {
          unsigned short* dst = (seg == 0) ? (unsigned short*)C0 : C1;
#pragma unroll
          for (int r = 0; r < 4; ++r)
            dst[(size_t)(row0 + r) * D_DIM + c2] = f2bf(acc[mi][ni][r] + bv);
        }
      }
    } else {
      float* out = (float*)C0;
#pragma unroll
      for (int mi = 0; mi < 4; ++mi) {
        int row0 = bm * 128 + wr * 64 + mi * 16 + lg * 4;
#pragma unroll
        for (int r = 0; r < 4; ++r)
          out[(size_t)(row0 + r) * N + col] = acc[mi][ni][r] + bv;
      }
    }
  }
}

// ---------------- merged RMSNorm+RoPE for Q (linear out) and K (head-blocked out) ----------------
__global__ __launch_bounds__(256) void norm_rope2(
    const unsigned short* __restrict__ qin, const unsigned short* __restrict__ kin,
    const float* __restrict__ qnw, const float* __restrict__ knw,
    const float* __restrict__ cosb, const float* __restrict__ sinb,
    unsigned short* __restrict__ qout, unsigned short* __restrict__ kout,
    float qscale) {
  const int isK = blockIdx.x >> 12;                // grid = 2*MROWS
  const int row = blockIdx.x & (MROWS - 1);
  const int pos = row & (S_LEN - 1);
  const unsigned short* hr = (isK ? kin : qin) + (size_t)row * D_DIM;
  const float* w = isK ? knw : qnw;
  const float outscale = isK ? 1.0f : qscale;
  const int t = threadIdx.x;
  const int d = t * 8;

  u16x8 hv = *reinterpret_cast<const u16x8*>(hr + d);
  float a[8];
#pragma unroll
  for (int i = 0; i < 8; ++i) a[i] = bf2f(hv[i]);
  float ss = 0.f;
#pragma unroll
  for (int i = 0; i < 8; ++i) ss += a[i] * a[i];
#pragma unroll
  for (int off = 32; off > 0; off >>= 1) ss += __shfl_down(ss, off);
  __shared__ float red[4];
  if ((t & 63) == 0) red[t >> 6] = ss;
  __syncthreads();
  float tot = red[0] + red[1] + red[2] + red[3];
  float inv = rsqrtf(tot * (1.0f / D_DIM) + 1e-6f) * outscale;

  const int p = (d & (HD - 1)) >> 1;
  const float* cp = cosb + pos * HALF + p;
  const float* sp = sinb + pos * HALF + p;
  const float* wp = w + d;

  float c0 = cp[0], c1 = cp[1], c2 = cp[2], c3 = cp[3];
  float s0 = sp[0], s1 = sp[1], s2 = sp[2], s3 = sp[3];
#pragma unroll
  for (int i = 0; i < 8; ++i) a[i] = a[i] * inv * wp[i];
  u16x8 o;
  o[0] = f2bf(a[0] * c0 - a[1] * s0);
  o[1] = f2bf(a[0] * s0 + a[1] * c0);
  o[2] = f2bf(a[2] * c1 - a[3] * s1);
  o[3] = f2bf(a[2] * s1 + a[3] * c1);
  o[4] = f2bf(a[4] * c2 - a[5] * s2);
  o[5] = f2bf(a[4] * s2 + a[5] * c2);
  o[6] = f2bf(a[6] * c3 - a[7] * s3);
  o[7] = f2bf(a[6] * s3 + a[7] * c3);
  if (isK) {
    int hh = t >> 4;
    int dd = d & (HD - 1);
    size_t oi = (((size_t)((row >> 11) * NHEAD + hh) * S_LEN) + pos) * HD + dd;
    *reinterpret_cast<u16x8*>(kout + oi) = o;
  } else {
    *reinterpret_cast<u16x8*>(qout + (size_t)row * D_DIM + d) = o;
  }
}

// ---------------- flash attention: 8 waves x 32q (QBLK=256), KVBLK=128 ----------------
// (unchanged from round 13)
__global__ __launch_bounds__(512) void attn_kernel(
    const unsigned short* __restrict__ Q, const unsigned short* __restrict__ Kh,
    const unsigned short* __restrict__ Vt, unsigned short* __restrict__ O) {
  const int idx = blockIdx.x;
  const int swz = (idx & 7) * 32 + (idx >> 3);   // 256 blocks, 32/XCD (4 heads)
  const int qb = swz & 7;
  const int h = (swz >> 3) & 15;
  const int b = swz >> 7;

  const int tid = threadIdx.x;
  const int lane = tid & 63;
  const int wave = tid >> 6;          // 0..7
  const int l31 = lane & 31;
  const int hh = lane >> 5;

  const size_t qbase = (size_t)b * S_LEN * D_DIM + (size_t)h * HD;   // linear Q/O
  const size_t hbase = (size_t)(b * NHEAD + h) * S_LEN * HD;         // blocked K/V
  const int q0w = qb * 256 + wave * 32;

  __shared__ __align__(16) unsigned short Ks[2 * 128 * 128];  // 2 x 32KB (dbuf)
  __shared__ __align__(16) unsigned short Vs[2 * 128 * 64];   // 32KB (2 s-halves)

  bf16x8 qf[8];
#pragma unroll
  for (int ds_ = 0; ds_ < 8; ++ds_)
    qf[ds_] = *reinterpret_cast<const bf16x8*>(
        Q + qbase + (size_t)(q0w + l31) * D_DIM + ds_ * 16 + hh * 8);

  f32x16 oacc[4] = {};
  float mrow = -1e30f, lrow = 0.f;

  const int pbase = wave * 1024 + (lane << 4);   // + j*8192, j=0..3 -> [0,32768)

  auto stageK = [&](int buf, int tix) {
    const unsigned short* ksrc = Kh + hbase + (size_t)tix * (128 * HD);
#pragma unroll
    for (int j = 0; j < 4; ++j) {
      int p = pbase + j * 8192;
      int kr = p >> 8;                                   // row 0..127 (256B rows)
      int kc = ((p >> 4) & 15) ^ ((kr & 7) ^ ((kr >> 3) & 7));
      gll16(ksrc + kr * 128 + kc * 8, (char*)Ks + buf * 32768 + p);
    }
  };
  auto stageV = [&](int tix) {
    const unsigned short* vsrc = Vt + hbase + (size_t)tix * (128 * HD);  // 2 v-tiles
#pragma unroll
    for (int j = 0; j < 4; ++j) {
      int p = pbase + j * 8192;
      int vr = (p & 16383) >> 7;                         // d-row 0..127 (128B rows)
      int vc = ((p >> 4) & 7) ^ (((vr & 7) ^ ((vr >> 3) & 7)) & 7);
      gll16(vsrc + (p >> 14) * (64 * HD) + vr * 64 + vc * 8, (char*)Vs + p);
    }
  };

  stageK(0, 0);   // 4 K-loads in flight

  const int NT = S_LEN / 128;          // 16
  for (int t = 0; t < NT; ++t) {
    const int cur = t & 1;
    stageV(t);                                          // +4 (V(t))
    stageK(cur ^ 1, (t + 1 < NT) ? t + 1 : t);          // +4 (K(t+1))
    asm volatile("s_waitcnt vmcnt(8)" ::: "memory");    // drain K(t) (oldest 4)
    __builtin_amdgcn_sched_barrier(0);
    __builtin_amdgcn_s_barrier();          // BAR1: K(t) visible
    __builtin_amdgcn_sched_barrier(0);

    // ---- QK^T swapped: sc[j] = P[k = 32j..32j+31][q = l31]
    const char* kbp = (const char*)Ks + cur * 32768;
    f32x16 sc[4] = {};
    __builtin_amdgcn_s_setprio(1);
#pragma unroll
    for (int ds_ = 0; ds_ < 8; ++ds_) {
#pragma unroll
      for (int j = 0; j < 4; ++j) {
        int r = j * 32 + l31;
        bf16x8 kf = *reinterpret_cast<const bf16x8*>(
            kbp + r * 256 + (((ds_ * 2 + hh) ^ ((r & 7) ^ ((r >> 3) & 7))) << 4));
        sc[j] = __builtin_amdgcn_mfma_f32_32x32x16_bf16(kf, qf[ds_], sc[j], 0, 0, 0);
      }
    }
    __builtin_amdgcn_s_setprio(0);

    // ---- online softmax (per-lane q-row = l31), tree reductions over 64 vals
    float m0[16];
#pragma unroll
    for (int r = 0; r < 16; ++r)
      m0[r] = fmaxf(fmaxf(sc[0][r], sc[1][r]), fmaxf(sc[2][r], sc[3][r]));
#pragma unroll
    for (int r = 0; r < 8; ++r) m0[r] = fmaxf(m0[r], m0[r + 8]);
#pragma unroll
    for (int r = 0; r < 4; ++r) m0[r] = fmaxf(m0[r], m0[r + 4]);
    float mx = fmaxf(fmaxf(m0[0], m0[1]), fmaxf(m0[2], m0[3]));
    mx = fmaxf(mx, __shfl_xor(mx, 32));
    if (__any(mx > mrow + 8.0f)) {          // defer-max rescale (rare)
      float nm = fmaxf(mrow, mx);
      float alpha = exp2f(mrow - nm);
      mrow = nm;
      lrow *= alpha;
#pragma unroll
      for (int r = 0; r < 16; ++r) {
        int qr = (r & 3) + 8 * (r >> 2) + 4 * hh;
        float av = __shfl(alpha, qr);
        oacc[0][r] *= av; oacc[1][r] *= av; oacc[2][r] *= av; oacc[3][r] *= av;
      }
    }
#pragma unroll
    for (int j = 0; j < 4; ++j)
#pragma unroll
      for (int r = 0; r < 16; ++r) sc[j][r] = exp2f(sc[j][r] - mrow);
    float s0[16];
#pragma unroll
    for (int r = 0; r < 16; ++r)
      s0[r] = (sc[0][r] + sc[1][r]) + (sc[2][r] + sc[3][r]);
#pragma unroll
    for (int r = 0; r < 8; ++r) s0[r] += s0[r + 8];
#pragma unroll
    for (int r = 0; r < 4; ++r) s0[r] += s0[r + 4];
    lrow += (s0[0] + s0[1]) + (s0[2] + s0[3]);

    // ---- P -> bf16 A-frags in-register (cvt_pk + permlane32_swap)
    uint32_t w[32];
#pragma unroll
    for (int X = 0; X < 4; ++X) {
#pragma unroll
      for (int g = 0; g < 4; ++g) {
        uint32_t lo, hi;
        float a0 = sc[X][4 * g], a1 = sc[X][4 * g + 1];
        float a2 = sc[X][4 * g + 2], a3 = sc[X][4 * g + 3];
        asm("v_cvt_pk_bf16_f32 %0, %1, %2" : "=v"(lo) : "v"(a0), "v"(a1));
        asm("v_cvt_pk_bf16_f32 %0, %1, %2" : "=v"(hi) : "v"(a2), "v"(a3));
        w[X * 8 + g * 2] = lo; w[X * 8 + g * 2 + 1] = hi;
      }
    }
    bf16x8 pa[8];
#pragma unroll
    for (int s = 0; s < 8; ++s) {
      int wb = (s >> 1) * 8 + (s & 1) * 4;
      uint32_t le = w[wb], he = w[wb + 1], lo_ = w[wb + 2], ho = w[wb + 3];
      asm("v_permlane32_swap_b32 %0, %1" : "+v"(le), "+v"(lo_));
      asm("v_permlane32_swap_b32 %0, %1" : "+v"(he), "+v"(ho));
      u32x4 fr = {le, he, lo_, ho};
      pa[s] = __builtin_bit_cast(bf16x8, fr);
    }

    // ---- wait V(t) (drains to 4: K(t+1) stays in flight), then barrier
    asm volatile("s_waitcnt vmcnt(4)" ::: "memory");
    __builtin_amdgcn_sched_barrier(0);
    __builtin_amdgcn_s_barrier();          // BAR-mid: V(t) visible
    __builtin_amdgcn_sched_barrier(0);

    // ---- PV: O[q][d] += P[q][k] V[k][d], k 0..127 in 8 slots
    const char* vbp = (const char*)Vs;
    __builtin_amdgcn_s_setprio(1);
#pragma unroll
    for (int db = 0; db < 4; ++db) {
      int d = db * 32 + l31;
      int fv = ((d & 7) ^ ((d >> 3) & 7)) & 7;
#pragma unroll
      for (int ks = 0; ks < 8; ++ks) {
        bf16x8 vv = *reinterpret_cast<const bf16x8*>(
            vbp + (ks >> 2) * 16384 + d * 128 + ((((ks & 3) * 2 + hh) ^ fv) << 4));
        oacc[db] = __builtin_amdgcn_mfma_f32_32x32x16_bf16(pa[ks], vv, oacc[db], 0, 0, 0);
      }
    }
    __builtin_amdgcn_s_setprio(0);

    __builtin_amdgcn_sched_barrier(0);
    __builtin_amdgcn_s_barrier();          // BAR2: Vs + Ks[cur] reads done
    __builtin_amdgcn_sched_barrier(0);
  }

  // ---- epilogue: reduce l across halves, normalize, store
  lrow += __shfl_xor(lrow, 32);
  float inv_[16];
#pragma unroll
  for (int r = 0; r < 16; ++r) {
    int qr = (r & 3) + 8 * (r >> 2) + 4 * hh;
    inv_[r] = 1.0f / __shfl(lrow, qr);
  }
#pragma unroll
  for (int db = 0; db < 4; ++db) {
#pragma unroll
    for (int r = 0; r < 16; ++r) {
      int qr = (r & 3) + 8 * (r >> 2) + 4 * hh;
      O[qbase + (size_t)(q0w + qr) * D_DIM + db * 32 + l31] =
          f2bf(oacc[db][r] * inv_[r]);
    }
  }
}

// ---------------- launch ----------------
extern "C" void kernel_launch(void* const* d_in, const int* in_sizes, int n_in,
                              void* d_out, int out_size, void* d_ws, size_t ws_size,
                              hipStream_t stream) {
  const float* x   = (const float*)d_in[0];
  const float* fc  = (const float*)d_in[1];
  const float* fs  = (const float*)d_in[2];
  const float* qw  = (const float*)d_in[3];
  const float* qb  = (const float*)d_in[4];
  const float* kw  = (const float*)d_in[5];
  const float* kb  = (const float*)d_in[6];
  const float* vw  = (const float*)d_in[7];
  const float* vb  = (const float*)d_in[8];
  const float* ow  = (const float*)d_in[9];
  const float* ob  = (const float*)d_in[10];
  const float* qnw = (const float*)d_in[11];
  const float* knw = (const float*)d_in[12];
  float* out = (float*)d_out;

  const size_t MSD = (size_t)MROWS * D_DIM;
  const size_t WSZ = (size_t)D_DIM * D_DIM;
  char* ws = (char*)d_ws;
  unsigned short* xb   = (unsigned short*)ws; ws += MSD * 2;
  unsigned short* qwb  = (unsigned short*)ws; ws += WSZ * 2;   // qwb,kwb,vwb contiguous
  unsigned short* kwb  = (unsigned short*)ws; ws += WSZ * 2;   //   = Bt[6144][2048]
  unsigned short* vwb  = (unsigned short*)ws; ws += WSZ * 2;
  unsigned short* owb  = (unsigned short*)ws; ws += WSZ * 2;
  float*          cbias = (float*)ws;         ws += 3 * D_DIM * 4;
  unsigned short* qpre = (unsigned short*)ws; ws += MSD * 2;   // bf16 pre-norm Q
  unsigned short* kpre = (unsigned short*)ws; ws += MSD * 2;   // bf16 pre-norm K
  unsigned short* qb16 = (unsigned short*)ws; ws += MSD * 2;
  unsigned short* kb16 = (unsigned short*)ws; ws += MSD * 2;   // Kh[b][h][s][d]
  unsigned short* vt16 = (unsigned short*)ws; ws += MSD * 2;   // Vt2[b][h][s/64][d][s%64]
  unsigned short* ob16 = (unsigned short*)ws; ws += MSD * 2;

  cast_all<<<2048, 256, 0, stream>>>(x, qw, kw, vw, ow, xb, qwb, kwb, vwb, owb);
  hipMemcpyAsync(cbias,              qb, D_DIM * sizeof(float), hipMemcpyDeviceToDevice, stream);
  hipMemcpyAsync(cbias + D_DIM,      kb, D_DIM * sizeof(float), hipMemcpyDeviceToDevice, stream);
  hipMemcpyAsync(cbias + 2 * D_DIM,  vb, D_DIM * sizeof(float), hipMemcpyDeviceToDevice, stream);

  // fused QKV projection: M=4096, N=6144, K=2048 -> 1536 blocks (~6/CU)
  gemm_bt<3><<<dim3((MROWS / 128) * (3 * D_DIM / 128)), 256, 0, stream>>>(
      xb, qwb, cbias, qpre, kpre, vt16, MROWS, 3 * D_DIM, D_DIM);

  const float qscale = 0.08838834764831845f * 1.4426950408889634f;
  norm_rope2<<<2 * MROWS, 256, 0, stream>>>(qpre, kpre, qnw, knw, fc, fs,
                                            qb16, kb16, qscale);

  attn_kernel<<<dim3(S_LEN / 256 * NHEAD * B_SZ), 512, 0, stream>>>(qb16, kb16, vt16, ob16);

  // output projection: M=4096, N=2048 -> 512 blocks
  gemm_bt<0><<<dim3((MROWS / 128) * (D_DIM / 128)), 256, 0, stream>>>(
      ob16, owb, ob, out, nullptr, nullptr, MROWS, D_DIM, D_DIM);
}

// Round 15
// 291.196 us; speedup vs baseline: 1.2548x; 1.1091x over previous
//
#include <hip/hip_runtime.h>
#include <stdint.h>

#define B_SZ 2
#define S_LEN 2048
#define D_DIM 2048
#define NHEAD 16
#define HD 128
#define HALF 64
#define MROWS (B_SZ * S_LEN)   // 4096

typedef __attribute__((ext_vector_type(8))) __bf16 bf16x8;
typedef __attribute__((ext_vector_type(8))) unsigned short u16x8;
typedef __attribute__((ext_vector_type(4))) float f32x4;
typedef __attribute__((ext_vector_type(16))) float f32x16;
typedef __attribute__((ext_vector_type(4))) unsigned int u32x4;

__device__ inline unsigned short f2bf(float x) {
  union { float f; uint32_t u; } c; c.f = x;
  uint32_t r = (c.u + 0x7fffu + ((c.u >> 16) & 1u)) >> 16;
  return (unsigned short)r;
}

__device__ inline float bf2f(unsigned short b) {
  union { uint32_t u; float f; } c; c.u = (uint32_t)b << 16;
  return c.f;
}

__device__ inline void gll16(const void* g, void* l) {
  __builtin_amdgcn_global_load_lds(
      (const __attribute__((address_space(1))) void*)g,
      (__attribute__((address_space(3))) void*)l,
      16, 0, 0);
}

// ---------------- fused cast f32 -> bf16 for x + 4 weight matrices ----------------
__global__ void cast_all(const float* __restrict__ x,
                         const float* __restrict__ qw, const float* __restrict__ kw,
                         const float* __restrict__ vw, const float* __restrict__ ow,
                         unsigned short* __restrict__ xb,
                         unsigned short* __restrict__ qwb, unsigned short* __restrict__ kwb,
                         unsigned short* __restrict__ vwb, unsigned short* __restrict__ owb) {
  const int n_x = (MROWS * D_DIM) / 4;
  const int n_w = (D_DIM * D_DIM) / 4;      // == 1<<20
  const int total = n_x + 4 * n_w;
  int i = blockIdx.x * blockDim.x + threadIdx.x;
  int stride = gridDim.x * blockDim.x;
  for (; i < total; i += stride) {
    const float* src; unsigned short* dst; int off;
    if (i < n_x) { src = x; dst = xb; off = i; }
    else {
      int j = i - n_x;
      int seg = j >> 20;
      off = j & (n_w - 1);
      src = seg == 0 ? qw : seg == 1 ? kw : seg == 2 ? vw : ow;
      dst = seg == 0 ? qwb : seg == 1 ? kwb : seg == 2 ? vwb : owb;
    }
    float4 v = reinterpret_cast<const float4*>(src)[off];
    ushort4 o;
    o.x = f2bf(v.x); o.y = f2bf(v.y); o.z = f2bf(v.z); o.w = f2bf(v.w);
    reinterpret_cast<ushort4*>(dst)[off] = o;
  }
}

// ---------------- GEMM 128x128 tile, BK=64 + T2 XOR swizzle, 4 waves ----------------
// C[i,j] = sum_k A[i,k]*Bt[j,k] + bias[j].
// Round-14 change: BK 32->64 (halves barrier/vmcnt-drain rounds, the m97
// structure's ~20% stall) + st-style XOR swizzle chunk^=(row&7) on BOTH the
// gll16 global source and the ds_read (involution verified in rounds 11/12's
// gemm256). LDS 32KB -> 5 blocks/CU. bn-major XCD chunk map kept (B panels
// L2-resident per XCD; A shared via L3).
// MODE 0: fp32 linear out -> C0.
// MODE 3: QKV fused (N=6144): seg0 -> (ushort*)C0 bf16 linear, seg1 -> C1 bf16
//         linear, seg2 -> C2 = Vt2[b][h][s/64][d][s%64].
template <int MODE>
__global__ __launch_bounds__(256) void gemm_bt(
    const unsigned short* __restrict__ A, const unsigned short* __restrict__ Bt,
    const float* __restrict__ bias, void* __restrict__ C0,
    unsigned short* __restrict__ C1, unsigned short* __restrict__ C2,
    int M, int N, int K) {
  __shared__ __align__(16) unsigned short As[128 * 64];   // 16KB
  __shared__ __align__(16) unsigned short Bs[128 * 64];   // 16KB
  const int tid = threadIdx.x;
  const int lane = tid & 63;
  const int wave = tid >> 6;
  const int nbn = N >> 7;
  const int xcd = blockIdx.x & 7;
  const int w = blockIdx.x >> 3;        // 0..chunk-1, chunk = 32*(nbn/8)
  const int bm = w & 31;                // M = 4096 -> 32 bm panels
  const int bn = xcd * (nbn >> 3) + (w >> 5);
  const int wr = wave >> 1, wc = wave & 1;
  const int lm = lane & 15, lg = lane >> 4;

  f32x4 acc[4][4] = {};

  for (int k0 = 0; k0 < K; k0 += 64) {
    __syncthreads();
#pragma unroll
    for (int r = 0; r < 4; ++r) {
      int p = r * 4096 + tid * 16;           // byte pos in 16KB tile
      int row = p >> 7;                      // 128B rows (64 bf16)
      int ch = (p >> 4) & 7;                 // 16B chunk in row
      int sc = (ch ^ (row & 7)) << 3;        // pre-swizzled source col (elems)
      gll16(A + (size_t)(bm * 128 + row) * K + k0 + sc, (char*)As + p);
      gll16(Bt + (size_t)(bn * 128 + row) * K + k0 + sc, (char*)Bs + p);
    }
    __syncthreads();

#pragma unroll
    for (int kk = 0; kk < 2; ++kk) {
      bf16x8 af[4], bfr[4];
#pragma unroll
      for (int mi = 0; mi < 4; ++mi) {
        int row = wr * 64 + mi * 16 + lm;
        af[mi] = *reinterpret_cast<const bf16x8*>(
            (const char*)As + row * 128 + ((((kk << 2) + lg) ^ (row & 7)) << 4));
      }
#pragma unroll
      for (int ni = 0; ni < 4; ++ni) {
        int row = wc * 64 + ni * 16 + lm;
        bfr[ni] = *reinterpret_cast<const bf16x8*>(
            (const char*)Bs + row * 128 + ((((kk << 2) + lg) ^ (row & 7)) << 4));
      }
#pragma unroll
      for (int mi = 0; mi < 4; ++mi)
#pragma unroll
        for (int ni = 0; ni < 4; ++ni)
          acc[mi][ni] = __builtin_amdgcn_mfma_f32_16x16x32_bf16(
              af[mi], bfr[ni], acc[mi][ni], 0, 0, 0);
    }
  }

#pragma unroll
  for (int ni = 0; ni < 4; ++ni) {
    int col = bn * 128 + wc * 64 + ni * 16 + lm;
    float bv = bias[col];
    if constexpr (MODE == 3) {
      int seg = col >> 11;            // 0=Q, 1=K, 2=V
      int c2 = col & (D_DIM - 1);
#pragma unroll
      for (int mi = 0; mi < 4; ++mi) {
        int row0 = bm * 128 + wr * 64 + mi * 16 + lg * 4;
        if (seg == 2) {
          int b = row0 >> 11, s0 = row0 & (S_LEN - 1);
          int h = c2 >> 7, d = c2 & (HD - 1);
          ushort4 o;
          o.x = f2bf(acc[mi][ni][0] + bv);
          o.y = f2bf(acc[mi][ni][1] + bv);
          o.z = f2bf(acc[mi][ni][2] + bv);
          o.w = f2bf(acc[mi][ni][3] + bv);
          size_t oi = ((((size_t)(b * NHEAD + h) * (S_LEN / 64) + (s0 >> 6)) * HD + d) << 6)
                      + (s0 & 63);
          *reinterpret_cast<ushort4*>(C2 + oi) = o;
        } else {
          unsigned short* dst = (seg == 0) ? (unsigned short*)C0 : C1;
#pragma unroll
          for (int r = 0; r < 4; ++r)
            dst[(size_t)(row0 + r) * D_DIM + c2] = f2bf(acc[mi][ni][r] + bv);
        }
      }
    } else {
      float* out = (float*)C0;
#pragma unroll
      for (int mi = 0; mi < 4; ++mi) {
        int row0 = bm * 128 + wr * 64 + mi * 16 + lg * 4;
#pragma unroll
        for (int r = 0; r < 4; ++r)
          out[(size_t)(row0 + r) * N + col] = acc[mi][ni][r] + bv;
      }
    }
  }
}

// ---------------- merged RMSNorm+RoPE for Q (linear out) and K (head-blocked out) ----------------
__global__ __launch_bounds__(256) void norm_rope2(
    const unsigned short* __restrict__ qin, const unsigned short* __restrict__ kin,
    const float* __restrict__ qnw, const float* __restrict__ knw,
    const float* __restrict__ cosb, const float* __restrict__ sinb,
    unsigned short* __restrict__ qout, unsigned short* __restrict__ kout,
    float qscale) {
  const int isK = blockIdx.x >> 12;                // grid = 2*MROWS
  const int row = blockIdx.x & (MROWS - 1);
  const int pos = row & (S_LEN - 1);
  const unsigned short* hr = (isK ? kin : qin) + (size_t)row * D_DIM;
  const float* w = isK ? knw : qnw;
  const float outscale = isK ? 1.0f : qscale;
  const int t = threadIdx.x;
  const int d = t * 8;

  u16x8 hv = *reinterpret_cast<const u16x8*>(hr + d);
  float a[8];
#pragma unroll
  for (int i = 0; i < 8; ++i) a[i] = bf2f(hv[i]);
  float ss = 0.f;
#pragma unroll
  for (int i = 0; i < 8; ++i) ss += a[i] * a[i];
#pragma unroll
  for (int off = 32; off > 0; off >>= 1) ss += __shfl_down(ss, off);
  __shared__ float red[4];
  if ((t & 63) == 0) red[t >> 6] = ss;
  __syncthreads();
  float tot = red[0] + red[1] + red[2] + red[3];
  float inv = rsqrtf(tot * (1.0f / D_DIM) + 1e-6f) * outscale;

  const int p = (d & (HD - 1)) >> 1;
  const float* cp = cosb + pos * HALF + p;
  const float* sp = sinb + pos * HALF + p;
  const float* wp = w + d;

  float c0 = cp[0], c1 = cp[1], c2 = cp[2], c3 = cp[3];
  float s0 = sp[0], s1 = sp[1], s2 = sp[2], s3 = sp[3];
#pragma unroll
  for (int i = 0; i < 8; ++i) a[i] = a[i] * inv * wp[i];
  u16x8 o;
  o[0] = f2bf(a[0] * c0 - a[1] * s0);
  o[1] = f2bf(a[0] * s0 + a[1] * c0);
  o[2] = f2bf(a[2] * c1 - a[3] * s1);
  o[3] = f2bf(a[2] * s1 + a[3] * c1);
  o[4] = f2bf(a[4] * c2 - a[5] * s2);
  o[5] = f2bf(a[4] * s2 + a[5] * c2);
  o[6] = f2bf(a[6] * c3 - a[7] * s3);
  o[7] = f2bf(a[6] * s3 + a[7] * c3);
  if (isK) {
    int hh = t >> 4;
    int dd = d & (HD - 1);
    size_t oi = (((size_t)((row >> 11) * NHEAD + hh) * S_LEN) + pos) * HD + dd;
    *reinterpret_cast<u16x8*>(kout + oi) = o;
  } else {
    *reinterpret_cast<u16x8*>(qout + (size_t)row * D_DIM + d) = o;
  }
}

// ---------------- flash attention: 8 waves x 32q (QBLK=256), KVBLK=128 ----------------
// (unchanged from round 13/14)
__global__ __launch_bounds__(512) void attn_kernel(
    const unsigned short* __restrict__ Q, const unsigned short* __restrict__ Kh,
    const unsigned short* __restrict__ Vt, unsigned short* __restrict__ O) {
  const int idx = blockIdx.x;
  const int swz = (idx & 7) * 32 + (idx >> 3);   // 256 blocks, 32/XCD (4 heads)
  const int qb = swz & 7;
  const int h = (swz >> 3) & 15;
  const int b = swz >> 7;

  const int tid = threadIdx.x;
  const int lane = tid & 63;
  const int wave = tid >> 6;          // 0..7
  const int l31 = lane & 31;
  const int hh = lane >> 5;

  const size_t qbase = (size_t)b * S_LEN * D_DIM + (size_t)h * HD;   // linear Q/O
  const size_t hbase = (size_t)(b * NHEAD + h) * S_LEN * HD;         // blocked K/V
  const int q0w = qb * 256 + wave * 32;

  __shared__ __align__(16) unsigned short Ks[2 * 128 * 128];  // 2 x 32KB (dbuf)
  __shared__ __align__(16) unsigned short Vs[2 * 128 * 64];   // 32KB (2 s-halves)

  bf16x8 qf[8];
#pragma unroll
  for (int ds_ = 0; ds_ < 8; ++ds_)
    qf[ds_] = *reinterpret_cast<const bf16x8*>(
        Q + qbase + (size_t)(q0w + l31) * D_DIM + ds_ * 16 + hh * 8);

  f32x16 oacc[4] = {};
  float mrow = -1e30f, lrow = 0.f;

  const int pbase = wave * 1024 + (lane << 4);   // + j*8192, j=0..3 -> [0,32768)

  auto stageK = [&](int buf, int tix) {
    const unsigned short* ksrc = Kh + hbase + (size_t)tix * (128 * HD);
#pragma unroll
    for (int j = 0; j < 4; ++j) {
      int p = pbase + j * 8192;
      int kr = p >> 8;                                   // row 0..127 (256B rows)
      int kc = ((p >> 4) & 15) ^ ((kr & 7) ^ ((kr >> 3) & 7));
      gll16(ksrc + kr * 128 + kc * 8, (char*)Ks + buf * 32768 + p);
    }
  };
  auto stageV = [&](int tix) {
    const unsigned short* vsrc = Vt + hbase + (size_t)tix * (128 * HD);  // 2 v-tiles
#pragma unroll
    for (int j = 0; j < 4; ++j) {
      int p = pbase + j * 8192;
      int vr = (p & 16383) >> 7;                         // d-row 0..127 (128B rows)
      int vc = ((p >> 4) & 7) ^ (((vr & 7) ^ ((vr >> 3) & 7)) & 7);
      gll16(vsrc + (p >> 14) * (64 * HD) + vr * 64 + vc * 8, (char*)Vs + p);
    }
  };

  stageK(0, 0);   // 4 K-loads in flight

  const int NT = S_LEN / 128;          // 16
  for (int t = 0; t < NT; ++t) {
    const int cur = t & 1;
    stageV(t);                                          // +4 (V(t))
    stageK(cur ^ 1, (t + 1 < NT) ? t + 1 : t);          // +4 (K(t+1))
    asm volatile("s_waitcnt vmcnt(8)" ::: "memory");    // drain K(t) (oldest 4)
    __builtin_amdgcn_sched_barrier(0);
    __builtin_amdgcn_s_barrier();          // BAR1: K(t) visible
    __builtin_amdgcn_sched_barrier(0);

    // ---- QK^T swapped: sc[j] = P[k = 32j..32j+31][q = l31]
    const char* kbp = (const char*)Ks + cur * 32768;
    f32x16 sc[4] = {};
    __builtin_amdgcn_s_setprio(1);
#pragma unroll
    for (int ds_ = 0; ds_ < 8; ++ds_) {
#pragma unroll
      for (int j = 0; j < 4; ++j) {
        int r = j * 32 + l31;
        bf16x8 kf = *reinterpret_cast<const bf16x8*>(
            kbp + r * 256 + (((ds_ * 2 + hh) ^ ((r & 7) ^ ((r >> 3) & 7))) << 4));
        sc[j] = __builtin_amdgcn_mfma_f32_32x32x16_bf16(kf, qf[ds_], sc[j], 0, 0, 0);
      }
    }
    __builtin_amdgcn_s_setprio(0);

    // ---- online softmax (per-lane q-row = l31), tree reductions over 64 vals
    float m0[16];
#pragma unroll
    for (int r = 0; r < 16; ++r)
      m0[r] = fmaxf(fmaxf(sc[0][r], sc[1][r]), fmaxf(sc[2][r], sc[3][r]));
#pragma unroll
    for (int r = 0; r < 8; ++r) m0[r] = fmaxf(m0[r], m0[r + 8]);
#pragma unroll
    for (int r = 0; r < 4; ++r) m0[r] = fmaxf(m0[r], m0[r + 4]);
    float mx = fmaxf(fmaxf(m0[0], m0[1]), fmaxf(m0[2], m0[3]));
    mx = fmaxf(mx, __shfl_xor(mx, 32));
    if (__any(mx > mrow + 8.0f)) {          // defer-max rescale (rare)
      float nm = fmaxf(mrow, mx);
      float alpha = exp2f(mrow - nm);
      mrow = nm;
      lrow *= alpha;
#pragma unroll
      for (int r = 0; r < 16; ++r) {
        int qr = (r & 3) + 8 * (r >> 2) + 4 * hh;
        float av = __shfl(alpha, qr);
        oacc[0][r] *= av; oacc[1][r] *= av; oacc[2][r] *= av; oacc[3][r] *= av;
      }
    }
#pragma unroll
    for (int j = 0; j < 4; ++j)
#pragma unroll
      for (int r = 0; r < 16; ++r) sc[j][r] = exp2f(sc[j][r] - mrow);
    float s0[16];
#pragma unroll
    for (int r = 0; r < 16; ++r)
      s0[r] = (sc[0][r] + sc[1][r]) + (sc[2][r] + sc[3][r]);
#pragma unroll
    for (int r = 0; r < 8; ++r) s0[r] += s0[r + 8];
#pragma unroll
    for (int r = 0; r < 4; ++r) s0[r] += s0[r + 4];
    lrow += (s0[0] + s0[1]) + (s0[2] + s0[3]);

    // ---- P -> bf16 A-frags in-register (cvt_pk + permlane32_swap)
    uint32_t w[32];
#pragma unroll
    for (int X = 0; X < 4; ++X) {
#pragma unroll
      for (int g = 0; g < 4; ++g) {
        uint32_t lo, hi;
        float a0 = sc[X][4 * g], a1 = sc[X][4 * g + 1];
        float a2 = sc[X][4 * g + 2], a3 = sc[X][4 * g + 3];
        asm("v_cvt_pk_bf16_f32 %0, %1, %2" : "=v"(lo) : "v"(a0), "v"(a1));
        asm("v_cvt_pk_bf16_f32 %0, %1, %2" : "=v"(hi) : "v"(a2), "v"(a3));
        w[X * 8 + g * 2] = lo; w[X * 8 + g * 2 + 1] = hi;
      }
    }
    bf16x8 pa[8];
#pragma unroll
    for (int s = 0; s < 8; ++s) {
      int wb = (s >> 1) * 8 + (s & 1) * 4;
      uint32_t le = w[wb], he = w[wb + 1], lo_ = w[wb + 2], ho = w[wb + 3];
      asm("v_permlane32_swap_b32 %0, %1" : "+v"(le), "+v"(lo_));
      asm("v_permlane32_swap_b32 %0, %1" : "+v"(he), "+v"(ho));
      u32x4 fr = {le, he, lo_, ho};
      pa[s] = __builtin_bit_cast(bf16x8, fr);
    }

    // ---- wait V(t) (drains to 4: K(t+1) stays in flight), then barrier
    asm volatile("s_waitcnt vmcnt(4)" ::: "memory");
    __builtin_amdgcn_sched_barrier(0);
    __builtin_amdgcn_s_barrier();          // BAR-mid: V(t) visible
    __builtin_amdgcn_sched_barrier(0);

    // ---- PV: O[q][d] += P[q][k] V[k][d], k 0..127 in 8 slots
    const char* vbp = (const char*)Vs;
    __builtin_amdgcn_s_setprio(1);
#pragma unroll
    for (int db = 0; db < 4; ++db) {
      int d = db * 32 + l31;
      int fv = ((d & 7) ^ ((d >> 3) & 7)) & 7;
#pragma unroll
      for (int ks = 0; ks < 8; ++ks) {
        bf16x8 vv = *reinterpret_cast<const bf16x8*>(
            vbp + (ks >> 2) * 16384 + d * 128 + ((((ks & 3) * 2 + hh) ^ fv) << 4));
        oacc[db] = __builtin_amdgcn_mfma_f32_32x32x16_bf16(pa[ks], vv, oacc[db], 0, 0, 0);
      }
    }
    __builtin_amdgcn_s_setprio(0);

    __builtin_amdgcn_sched_barrier(0);
    __builtin_amdgcn_s_barrier();          // BAR2: Vs + Ks[cur] reads done
    __builtin_amdgcn_sched_barrier(0);
  }

  // ---- epilogue: reduce l across halves, normalize, store
  lrow += __shfl_xor(lrow, 32);
  float inv_[16];
#pragma unroll
  for (int r = 0; r < 16; ++r) {
    int qr = (r & 3) + 8 * (r >> 2) + 4 * hh;
    inv_[r] = 1.0f / __shfl(lrow, qr);
  }
#pragma unroll
  for (int db = 0; db < 4; ++db) {
#pragma unroll
    for (int r = 0; r < 16; ++r) {
      int qr = (r & 3) + 8 * (r >> 2) + 4 * hh;
      O[qbase + (size_t)(q0w + qr) * D_DIM + db * 32 + l31] =
          f2bf(oacc[db][r] * inv_[r]);
    }
  }
}

// ---------------- launch ----------------
extern "C" void kernel_launch(void* const* d_in, const int* in_sizes, int n_in,
                              void* d_out, int out_size, void* d_ws, size_t ws_size,
                              hipStream_t stream) {
  const float* x   = (const float*)d_in[0];
  const float* fc  = (const float*)d_in[1];
  const float* fs  = (const float*)d_in[2];
  const float* qw  = (const float*)d_in[3];
  const float* qb  = (const float*)d_in[4];
  const float* kw  = (const float*)d_in[5];
  const float* kb  = (const float*)d_in[6];
  const float* vw  = (const float*)d_in[7];
  const float* vb  = (const float*)d_in[8];
  const float* ow  = (const float*)d_in[9];
  const float* ob  = (const float*)d_in[10];
  const float* qnw = (const float*)d_in[11];
  const float* knw = (const float*)d_in[12];
  float* out = (float*)d_out;

  const size_t MSD = (size_t)MROWS * D_DIM;
  const size_t WSZ = (size_t)D_DIM * D_DIM;
  char* ws = (char*)d_ws;
  unsigned short* xb   = (unsigned short*)ws; ws += MSD * 2;
  unsigned short* qwb  = (unsigned short*)ws; ws += WSZ * 2;   // qwb,kwb,vwb contiguous
  unsigned short* kwb  = (unsigned short*)ws; ws += WSZ * 2;   //   = Bt[6144][2048]
  unsigned short* vwb  = (unsigned short*)ws; ws += WSZ * 2;
  unsigned short* owb  = (unsigned short*)ws; ws += WSZ * 2;
  float*          cbias = (float*)ws;         ws += 3 * D_DIM * 4;
  unsigned short* qpre = (unsigned short*)ws; ws += MSD * 2;   // bf16 pre-norm Q
  unsigned short* kpre = (unsigned short*)ws; ws += MSD * 2;   // bf16 pre-norm K
  unsigned short* qb16 = (unsigned short*)ws; ws += MSD * 2;
  unsigned short* kb16 = (unsigned short*)ws; ws += MSD * 2;   // Kh[b][h][s][d]
  unsigned short* vt16 = (unsigned short*)ws; ws += MSD * 2;   // Vt2[b][h][s/64][d][s%64]
  unsigned short* ob16 = (unsigned short*)ws; ws += MSD * 2;

  cast_all<<<2048, 256, 0, stream>>>(x, qw, kw, vw, ow, xb, qwb, kwb, vwb, owb);
  hipMemcpyAsync(cbias,              qb, D_DIM * sizeof(float), hipMemcpyDeviceToDevice, stream);
  hipMemcpyAsync(cbias + D_DIM,      kb, D_DIM * sizeof(float), hipMemcpyDeviceToDevice, stream);
  hipMemcpyAsync(cbias + 2 * D_DIM,  vb, D_DIM * sizeof(float), hipMemcpyDeviceToDevice, stream);

  // fused QKV projection: M=4096, N=6144, K=2048 -> 1536 blocks (~5/CU)
  gemm_bt<3><<<dim3((MROWS / 128) * (3 * D_DIM / 128)), 256, 0, stream>>>(
      xb, qwb, cbias, qpre, kpre, vt16, MROWS, 3 * D_DIM, D_DIM);

  const float qscale = 0.08838834764831845f * 1.4426950408889634f;
  norm_rope2<<<2 * MROWS, 256, 0, stream>>>(qpre, kpre, qnw, knw, fc, fs,
                                            qb16, kb16, qscale);

  attn_kernel<<<dim3(S_LEN / 256 * NHEAD * B_SZ), 512, 0, stream>>>(qb16, kb16, vt16, ob16);

  // output projection: M=4096, N=2048 -> 512 blocks
  gemm_bt<0><<<dim3((MROWS / 128) * (D_DIM / 128)), 256, 0, stream>>>(
      ob16, owb, ob, out, nullptr, nullptr, MROWS, D_DIM, D_DIM);
}